// Round 11
// baseline (464.928 us; speedup 1.0000x reference)
//
#include <hip/hip_runtime.h>
#include <cfloat>

// VQ forward, MI355X. z[16,256,32,32] f32, emb[8192,256] f32, proj[256,256] f32.
// N = 16384 rows, K = 8192 codes, D = 256.
// d_out (floats): out[4194304] | loss | commitment | codebook_loss | idx_as_float[16384]
//
// R17 (393): single-pass scan, running-threshold emission, score-carrying slots
//  (quant19(sc-zn)<<13|k), final-threshold-filtered exact rescore.
// R18 (387): A-resident + seamless B stream + k_codebook float4 LDS reads.
// R19: ASYNC atomic exchange — the one change vs R18. R17/R18 showed the load
//  stream is not the critical path (199->207 on A-hoist); the per-quad chain
//  m2 -> SYNCHRONOUS device-scope atomicMin (~500-900 cyc cross-XCD round trip,
//  m126 HBM-class) -> thr -> emit was. Now:
//   - top of quad: lane ml<8 posts running min: oldg = atomicMin(rowminG[n],
//     runp) — latency hides UNDER the quad's 64-MFMA cluster;
//   - after fold: base = min(oldg, runp, m2) (monof domain), thr = base+DLT,
//     emit, runp = min(runp, m2);
//   - epilogue: fire-and-forget atomicMin(rowminG[n], runp) so final rowminG
//     includes the last quad (rescore filter tightness preserved).
//  Correctness: any base >= g_final, winner sc* <= g_final+2err <= base+DLT
//  (DLT=8e-4 > 2err=6.4e-4) -> always emitted under any staleness/race.
//  Freshness is one quad staler than R16's mid-quad atomic -> counts ~unchanged
//  (R16-18 measured fine at SLOTS=128; falsifier = WRITE_SIZE jump).

constexpr int Dd = 256;
constexpr float INV_M = 1.0f / 4194304.0f;
constexpr float DLT = 8e-4f;
constexpr int SLOTS = 128;

typedef unsigned short u16;
typedef unsigned int u32;
typedef __attribute__((ext_vector_type(8))) short short8;   // 8 bf16
typedef __attribute__((ext_vector_type(4))) float f32x4;

__device__ __forceinline__ unsigned monof(float f) {
  unsigned u = __float_as_uint(f);
  return (u & 0x80000000u) ? ~u : (u | 0x80000000u);
}
__device__ __forceinline__ float unmonof(unsigned p) {
  unsigned u = (p & 0x80000000u) ? (p & 0x7FFFFFFFu) : ~p;
  return __uint_as_float(u);
}
__device__ __forceinline__ u16 f2bf(float x) {   // RNE float->bf16 bits
  unsigned u = __float_as_uint(x);
  u += 0x7FFFu + ((u >> 16) & 1u);
  return (u16)(u >> 16);
}

// ---- K1: codebook = emb @ proj^T -> cb[k][d] fp32 + ef bf16 fragment-order ----
__global__ __launch_bounds__(256)
void k_codebook(const float* __restrict__ emb, const float* __restrict__ proj,
                float* __restrict__ cb, u16* __restrict__ ef) {
  __shared__ __align__(16) float et[64 * 68];
  __shared__ __align__(16) float pt[64 * 68];
  __shared__ __align__(16) u16 tileT[64 * 72];
  const int t = threadIdx.x;
  const int tx = t & 15, ty = t >> 4;
  const int kb = blockIdx.x * 64;
  const int db = blockIdx.y * 64;
  float acc[4][4];
#pragma unroll
  for (int u = 0; u < 4; ++u)
#pragma unroll
    for (int v = 0; v < 4; ++v) acc[u][v] = 0.f;

  const int jm = t & 15;
  const int q  = t >> 4;

  for (int jc = 0; jc < Dd; jc += 64) {
    __syncthreads();
#pragma unroll
    for (int i = 0; i < 4; ++i) {
      const int row = q + i * 16;
      const float4 e4 = *(const float4*)(emb  + (size_t)(kb + row) * Dd + jc + jm * 4);
      const float4 p4 = *(const float4*)(proj + (size_t)(db + row) * Dd + jc + jm * 4);
      et[(jm*4 + 0) * 68 + row] = e4.x;
      et[(jm*4 + 1) * 68 + row] = e4.y;
      et[(jm*4 + 2) * 68 + row] = e4.z;
      et[(jm*4 + 3) * 68 + row] = e4.w;
      pt[(jm*4 + 0) * 68 + row] = p4.x;
      pt[(jm*4 + 1) * 68 + row] = p4.y;
      pt[(jm*4 + 2) * 68 + row] = p4.z;
      pt[(jm*4 + 3) * 68 + row] = p4.w;
    }
    __syncthreads();
#pragma unroll 16
    for (int j = 0; j < 64; ++j) {
      const float4 a4 = *(const float4*)(et + j * 68 + ty * 4);
      const float4 b4 = *(const float4*)(pt + j * 68 + tx * 4);
      const float a[4] = {a4.x, a4.y, a4.z, a4.w};
      const float b[4] = {b4.x, b4.y, b4.z, b4.w};
#pragma unroll
      for (int u = 0; u < 4; ++u)
#pragma unroll
        for (int v = 0; v < 4; ++v) acc[u][v] = fmaf(a[u], b[v], acc[u][v]);
    }
  }
  // fp32 cb (linear) + bf16 tile to LDS for fragment-order shuffle
#pragma unroll
  for (int u = 0; u < 4; ++u) {
    const int k = kb + ty*4 + u;
#pragma unroll
    for (int v = 0; v < 4; ++v) {
      const int d = db + tx*4 + v;
      const float val = acc[u][v];
      cb[(size_t)k * Dd + d] = val;
      tileT[(ty*4 + u) * 72 + tx*4 + v] = f2bf(val);
    }
  }
  __syncthreads();
  // emit 512 fragment granules (16 B each), coalesced
  uint4* ef16 = (uint4*)ef;
#pragma unroll
  for (int w2 = 0; w2 < 2; ++w2) {
    const int uu = w2 * 256 + t;
    const int k16g = uu >> 7;            // 0..3 (16-k group within tile)
    const int d32g = (uu >> 6) & 1;      // 0..1 (32-d group within tile)
    const int ln   = uu & 63;            // fragment lane
    const int klo  = k16g * 16 + (ln & 15);
    const int dlo  = d32g * 32 + (ln >> 4) * 8;
    ef16[((kb >> 4) + k16g) * 512 + ((db >> 5) + d32g) * 64 + ln] =
        *(const uint4*)&tileT[klo * 72 + dlo];
  }
}

// ---- K1b: per-code norms (ascending-d fmaf chain) ----
__global__ __launch_bounds__(256)
void k_norms(const float* __restrict__ cb, float* __restrict__ norms) {
  const int k = blockIdx.x * 256 + threadIdx.x;
  const float* row = cb + (size_t)k * Dd;
  float s = 0.f;
  for (int d = 0; d < Dd; d += 4) {
    const float4 v = *(const float4*)(row + d);
    s = fmaf(v.x, v.x, s);
    s = fmaf(v.y, v.y, s);
    s = fmaf(v.z, v.z, s);
    s = fmaf(v.w, v.w, s);
  }
  norms[k] = s;
}

// ---- K1c: transpose z -> zf bf16 fragment-order + znorm ----
__global__ __launch_bounds__(256)
void k_prep_z(const float* __restrict__ z, u16* __restrict__ zf,
              float* __restrict__ znorm) {
  __shared__ float tile[256 * 33];
  const int t = threadIdx.x;
  const int blk = blockIdx.x;            // b*32 + h
  const int w = t & 31, rg = t >> 5;
  const size_t zbase = (size_t)(blk >> 5) * 262144 + (size_t)(blk & 31) * 32 + w;
#pragma unroll 8
  for (int i = 0; i < 32; ++i) {
    const int d = rg * 32 + i;
    tile[d * 33 + w] = z[zbase + (size_t)d * 1024];
  }
  __syncthreads();
  if (t < 32) {
    float s = 0.f;
    for (int d = 0; d < Dd; ++d) {
      const float v = tile[d * 33 + t];
      s = fmaf(v, v, s);
    }
    znorm[blk * 32 + t] = s;
  }
  // fragment-order write: granule U = ((n>>4)*8 + d32)*64 + qd*16 + (n&15)
  const int ml16 = t & 15;
  const int seg  = (t >> 4) & 7;         // d32 group
  const int hi   = t >> 7;               // n16 group within block (0/1)
  const int nl   = hi * 16 + ml16;       // row 0..31 within block
  uint4* zf16 = (uint4*)zf;
  const int ubase = ((blk * 2 + hi) * 8 + seg) * 64 + ml16;
#pragma unroll
  for (int j = 0; j < 4; ++j) {          // qd octet
    u16 hb[8];
#pragma unroll
    for (int e = 0; e < 8; ++e)
      hb[e] = f2bf(tile[(seg * 32 + j * 8 + e) * 33 + nl]);
    zf16[ubase + j * 16] = *(const uint4*)hb;
  }
}

// ---- K2: single-pass MFMA scan, async atomic exchange ----
// Block 64 rows x 1024 cols; wave (rowhalf,colhalf) = 32 rows x 128 cols.
__global__ __launch_bounds__(256, 2)
void k_scan(const u16* __restrict__ zf, const u16* __restrict__ ef,
            const float* __restrict__ norms, const float* __restrict__ znorm,
            u32* __restrict__ rowminG, u32* __restrict__ rowcnt,
            u32* __restrict__ slots) {
  const int t    = threadIdx.x;
  const int lane = t & 63;
  const int ml   = lane & 15;
  const int qd   = lane >> 4;
  const int wvu  = __builtin_amdgcn_readfirstlane(t >> 6);
  const int rowhalf = wvu & 1;           // 0/1 -> 32 rows
  const int colhalf = wvu >> 1;          // 0/1 -> 128 cols (of kt's 256)
  const int bid  = blockIdx.x;
  const int kb   = (bid & 7) * 1024;     // colgroup -> XCD-local ef reuse
  const int nb   = (bid >> 3) * 64;

  const uint4* zf16 = (const uint4*)zf;
  const uint4* ef16 = (const uint4*)ef;
  // B granule (kt,cq,ct,d32): eb + ((kt*16)+(cq*4)+ct)*512 + d32*64
  const uint4* eb = ef16 + (size_t)((kb >> 4) + colhalf * 8) * 512 + lane;

  // ---- A resident in VGPR: A[rt][d32], 16 granules = 64 VGPR, loaded once ----
  short8 A[2][8];
  {
    const uint4* za = zf16 + (size_t)((nb >> 4) + rowhalf * 2) * 512 + lane;
#pragma unroll
    for (int rt = 0; rt < 2; ++rt)
#pragma unroll
      for (int d32 = 0; d32 < 8; ++d32)
        A[rt][d32] = *(const short8*)(za + rt * 512 + d32 * 64);
  }

  // per-thread rows: n = nb + rowhalf*32 + rt*16 + qd*4 + r
  float zn[2][4];
#pragma unroll
  for (int rt = 0; rt < 2; ++rt) {
    const int nr = nb + rowhalf * 32 + rt * 16 + qd * 4;
    const f32x4 z4 = *(const f32x4*)(znorm + nr);
#pragma unroll
    for (int r = 0; r < 4; ++r) zn[rt][r] = z4[r];
  }

  // running per-row min (monof-packed; identical across the 16 ml lanes)
  unsigned runp[2][4];
#pragma unroll
  for (int rt = 0; rt < 2; ++rt)
#pragma unroll
    for (int r = 0; r < 4; ++r) runp[rt][r] = 0xFFFFFFFFu;

  // ---- seamless B stream: two buffers alternate by d32 parity across quads ----
  short8 Bb0[4], Bb1[4];
#pragma unroll
  for (int ct = 0; ct < 4; ++ct) Bb0[ct] = *(const short8*)(eb + ct * 512);

#pragma unroll 1
  for (int kt = 0; kt < 4; ++kt) {
    const size_t ekt = (size_t)kt * 16 * 512;
#pragma unroll
    for (int cq = 0; cq < 2; ++cq) {
      const uint4* ecq = eb + ekt + (size_t)(cq * 4) * 512;

      // ---- async exchange: post running min, read fresh global; latency
      //      hides under this quad's MFMA cluster (result used after fold).
      unsigned oldg = 0xFFFFFFFFu;
      if (ml < 8) {
        const int rt_ = ml >> 2, r_ = ml & 3;
        const int n = nb + rowhalf * 32 + rt_ * 16 + qd * 4 + r_;
        oldg = atomicMin(&rowminG[n], runp[rt_][r_]);
      }

      f32x4 acc[2][4];
#pragma unroll
      for (int rt = 0; rt < 2; ++rt)
#pragma unroll
        for (int ct = 0; ct < 4; ++ct) acc[rt][ct] = (f32x4)0.f;

#pragma unroll
      for (int d32 = 0; d32 < 8; ++d32) {
        // prefetch the NEXT stream step (possibly next quad / next kt):
        const bool last = (kt == 3) && (cq == 1) && (d32 == 7);
        if (!last) {
          const uint4* pnext;
          if (d32 < 7) {
            pnext = ecq + (d32 + 1) * 64;                  // same quad
          } else if (cq == 0) {
            pnext = eb + ekt + (size_t)4 * 512;            // quad cq=1, d32=0
          } else {
            pnext = eb + ekt + (size_t)16 * 512;           // next kt, cq=0, d32=0
          }
          if (d32 & 1) {
#pragma unroll
            for (int ct = 0; ct < 4; ++ct)
              Bb0[ct] = *(const short8*)(pnext + ct * 512);
          } else {
#pragma unroll
            for (int ct = 0; ct < 4; ++ct)
              Bb1[ct] = *(const short8*)(pnext + ct * 512);
          }
        }
        if (d32 & 1) {
#pragma unroll
          for (int ct = 0; ct < 4; ++ct)
#pragma unroll
            for (int rt = 0; rt < 2; ++rt)
              acc[rt][ct] = __builtin_amdgcn_mfma_f32_16x16x32_bf16(
                  A[rt][d32], Bb1[ct], acc[rt][ct], 0, 0, 0);
        } else {
#pragma unroll
          for (int ct = 0; ct < 4; ++ct)
#pragma unroll
            for (int rt = 0; rt < 2; ++rt)
              acc[rt][ct] = __builtin_amdgcn_mfma_f32_16x16x32_bf16(
                  A[rt][d32], Bb0[ct], acc[rt][ct], 0, 0, 0);
        }
      }

      // ---- scores in place: acc = (zn + nk) - 2*acc  (quantized fold) ----
#pragma unroll
      for (int ct = 0; ct < 4; ++ct) {
        const int k0 = kb + kt * 256 + colhalf * 128 + cq * 64 + ct * 16 + ml;
        const float nkv = norms[k0];
#pragma unroll
        for (int rt = 0; rt < 2; ++rt)
#pragma unroll
          for (int r = 0; r < 4; ++r)
            acc[rt][ct][r] = (zn[rt][r] + nkv) - 2.0f * acc[rt][ct][r];
      }

      // ---- per-row quad min (over ct, then over 16 ml lanes) ----
      float m2[2][4];
#pragma unroll
      for (int rt = 0; rt < 2; ++rt)
#pragma unroll
        for (int r = 0; r < 4; ++r) {
          float m = fminf(fminf(acc[rt][0][r], acc[rt][1][r]),
                          fminf(acc[rt][2][r], acc[rt][3][r]));
#pragma unroll
          for (int s = 1; s < 16; s <<= 1) m = fminf(m, __shfl_xor(m, s, 64));
          m2[rt][r] = m;
        }

      // ---- thr = min(oldg, runp, m2) + DLT  (monof domain; broadcast oldg) ----
      float thrv[2][4];
#pragma unroll
      for (int rt = 0; rt < 2; ++rt)
#pragma unroll
        for (int r = 0; r < 4; ++r) {
          const unsigned og = __shfl(oldg, (lane & 48) + rt * 4 + r, 64);
          const unsigned mp = monof(m2[rt][r]);
          const unsigned base = min(og, min(runp[rt][r], mp));
          thrv[rt][r] = unmonof(base) + DLT;
          runp[rt][r] = min(runp[rt][r], mp);
        }

      // ---- emit candidates: sc <= thr ----
      // slot payload: quant19(sc - zn) << 13 | k  (Sterbenz-exact sc-zn, 2^-21 res)
#pragma unroll
      for (int ct = 0; ct < 4; ++ct) {
        const int k = kb + kt * 256 + colhalf * 128 + cq * 64 + ct * 16 + ml;
#pragma unroll
        for (int rt = 0; rt < 2; ++rt)
#pragma unroll
          for (int r = 0; r < 4; ++r) {
            if (acc[rt][ct][r] <= thrv[rt][r]) {
              const int n = nb + rowhalf * 32 + rt * 16 + qd * 4 + r;
              const u32 pos = atomicAdd(&rowcnt[n], 1u);
              if (pos < (u32)SLOTS) {
                const float e = acc[rt][ct][r] - zn[rt][r];
                int q = __float2int_rn(e * 2097152.0f) + 262144;
                q = q < 0 ? 0 : (q > 524287 ? 524287 : q);
                slots[n * SLOTS + pos] = ((u32)q << 13) | (u32)k;
              }
            }
          }
      }
    }
    __syncthreads();   // bound wave drift: partner waves' duplicate B reads hit L1
  }

  // ---- epilogue: post final running min (incl. last quad) — fire-and-forget;
  //      keeps rowminG exact so k_rescore's filter stays tight.
  if (ml < 8) {
    const int rt_ = ml >> 2, r_ = ml & 3;
    const int n = nb + rowhalf * 32 + rt_ * 16 + qd * 4 + r_;
    atomicMin(&rowminG[n], runp[rt_][r_]);
  }
}

// ---- K2c: filtered exact rescore (full-scan fallback on overflow) ----
// Block per (b,h): 32 rows; LDS z-tile [32][261] fp32; wave per 8 rows.
__global__ __launch_bounds__(256)
void k_rescore(const float* __restrict__ z, const float* __restrict__ cb,
               const float* __restrict__ norms, const float* __restrict__ znorm,
               const u32* __restrict__ rowminG, const u32* __restrict__ rowcnt,
               const u32* __restrict__ slots,
               unsigned long long* __restrict__ packed) {
  __shared__ float ztl[32 * 261];
  const int t = threadIdx.x;
  const int blk = blockIdx.x;          // b*32 + h
  const int w = t & 31, dg = t >> 5;
  const size_t zbase = (size_t)(blk >> 5) * 262144 + (size_t)(blk & 31) * 32;
#pragma unroll 8
  for (int i = 0; i < 32; ++i) {
    const int d = dg * 32 + i;
    ztl[w * 261 + d] = z[zbase + (size_t)d * 1024 + w];
  }
  __syncthreads();

  const int lane = t & 63;
  const int wv = t >> 6;               // 4 waves
  // 4 waves x 8 rows each
#pragma unroll 1
  for (int i = 0; i < 8; ++i) {
    const int rl = wv * 8 + i;
    const int n = blk * 32 + rl;
    const u32 cnt = rowcnt[n];
    const float znr = znorm[n];
    const float* zp = ztl + rl * 261 + lane * 4;
    // final-threshold filter in encoded domain (+68 LSB covers all rounding)
    const float g = unmonof(rowminG[n]);
    const int qThr = __float2int_rn((g + DLT - znr) * 2097152.0f) + 262144 + 68;
    unsigned long long best = 0xFFFFFFFFFFFFFFFFull;
    if (cnt <= (u32)SLOTS) {
      for (u32 c = 0; c < cnt; ++c) {
        const u32 v = slots[n * SLOTS + c];      // wave-uniform addr -> broadcast
        if ((int)(v >> 13) > qThr) continue;     // uniform branch
        const int k = (int)(v & 8191u);
        const float4 c4 = *(const float4*)(cb + (size_t)k * Dd + lane * 4);
        float p = 0.f;
        p = fmaf(zp[0], c4.x, p);
        p = fmaf(zp[1], c4.y, p);
        p = fmaf(zp[2], c4.z, p);
        p = fmaf(zp[3], c4.w, p);
#pragma unroll
        for (int s = 1; s < 64; s <<= 1) p += __shfl_xor(p, s, 64);
        const float sc = (znr + norms[k]) - 2.0f * p;   // quantized fold
        const unsigned long long pk =
            ((unsigned long long)monof(sc) << 32) | (unsigned)k;
        if (pk < best) best = pk;                        // ties -> min k
      }
    } else {
      // overflow fallback (never expected): exact scan of all 8192 codes
      for (int k = 0; k < 8192; ++k) {
        const float4 c4 = *(const float4*)(cb + (size_t)k * Dd + lane * 4);
        float p = 0.f;
        p = fmaf(zp[0], c4.x, p);
        p = fmaf(zp[1], c4.y, p);
        p = fmaf(zp[2], c4.z, p);
        p = fmaf(zp[3], c4.w, p);
#pragma unroll
        for (int s = 1; s < 64; s <<= 1) p += __shfl_xor(p, s, 64);
        const float sc = (znr + norms[k]) - 2.0f * p;
        const unsigned long long pk =
            ((unsigned long long)monof(sc) << 32) | (unsigned)k;
        if (pk < best) best = pk;
      }
    }
    if (lane == 0 && cnt > 0) packed[n] = best;
  }
}

// ---- K3: gather codes, write out (NCHW), idx floats, reduce SSE ----
__global__ __launch_bounds__(256)
void k_output(const float* __restrict__ z, const float* __restrict__ cb,
              const unsigned long long* __restrict__ packed,
              float* __restrict__ out, float* __restrict__ idxf,
              float* __restrict__ ssum) {
  __shared__ float zqT[256 * 33];
  __shared__ float part[4];
  const int t = threadIdx.x;
  const int blk = blockIdx.x;       // = b*32 + h
  const int nbase = blk * 32;

  {
    const int nl = t >> 3, m = t & 7;
    // guard the GATHER address only (&8191): if upstream ever leaves the
    // sentinel, we return wrong values (checker catches) instead of faulting.
    const int idx = (int)(packed[nbase + nl] & 0xFFFFFFFFull) & 8191;
    const float* row = cb + (size_t)idx * Dd;
#pragma unroll
    for (int i = 0; i < 8; ++i) {
      const int d0 = m * 4 + i * 32;
      const float4 v = *(const float4*)(row + d0);
      zqT[(d0 + 0) * 33 + nl] = v.x;
      zqT[(d0 + 1) * 33 + nl] = v.y;
      zqT[(d0 + 2) * 33 + nl] = v.z;
      zqT[(d0 + 3) * 33 + nl] = v.w;
    }
    if (t < 32)
      idxf[nbase + t] = (float)(unsigned)(packed[nbase + t] & 0xFFFFFFFFull);
  }
  __syncthreads();

  const int w = t & 31, cg = t >> 5;
  const size_t base = (size_t)(blk >> 5) * 262144 + (size_t)(blk & 31) * 32 + w;
  float local = 0.f;
#pragma unroll
  for (int cc = 0; cc < 32; ++cc) {
    const int c = cg * 32 + cc;
    const float q  = zqT[c * 33 + w];
    const float zv = z[base + (size_t)c * 1024];
    out[base + (size_t)c * 1024] = q;
    const float dd = q - zv;
    local = fmaf(dd, dd, local);
  }
  float v = local;
#pragma unroll
  for (int m = 1; m < 64; m <<= 1) v += __shfl_xor(v, m, 64);
  if ((t & 63) == 0) part[t >> 6] = v;
  __syncthreads();
  if (t == 0) atomicAdd(ssum, part[0] + part[1] + part[2] + part[3]);
}

// ---- K4: finalize scalars ----
__global__ void k_final(const float* __restrict__ ssum, float* __restrict__ scal) {
  const float m = *ssum * INV_M;
  scal[0] = 1.25f * m;   // loss
  scal[1] = 0.25f * m;   // commitment_loss
  scal[2] = m;           // codebook_loss
}

extern "C" void kernel_launch(void* const* d_in, const int* in_sizes, int n_in,
                              void* d_out, int out_size, void* d_ws, size_t ws_size,
                              hipStream_t stream) {
  const float* z    = (const float*)d_in[0];
  const float* emb  = (const float*)d_in[1];
  const float* proj = (const float*)d_in[2];

  float* out  = (float*)d_out;
  float* scal = out + 4194304;
  float* idxf = out + 4194307;

  // ws (~28.9 MB): cb | norms | packed | znorm | zf | ef | rowminG | rowcnt | slots(u32) | ssum
  float* cb    = (float*)d_ws;                          // 8 MB
  float* norms = cb + 2097152;                          // 32 KB
  unsigned long long* packed =
      (unsigned long long*)(norms + 8192);              // 128 KB
  float* znorm = (float*)(packed + 16384);              // 64 KB
  u16* zf = (u16*)(znorm + 16384);                      // 8.4 MB (fragment-order)
  u16* ef = zf + 4194304;                               // 4.2 MB (fragment-order)
  u32* rowminG = (u32*)(ef + 2097152);                  // 64 KB
  u32* rowcnt = rowminG + 16384;                        // 64 KB
  u32* slots = rowcnt + 16384;                          // 8 MB (128 u32/row)
  float* ssum = (float*)(slots + (size_t)16384 * SLOTS);// 4 B

  hipMemsetAsync(rowminG, 0xFF, 16384 * sizeof(u32), stream);
  hipMemsetAsync(rowcnt, 0, 16384 * sizeof(u32), stream);
  hipMemsetAsync(packed, 0xFF, 16384 * sizeof(unsigned long long), stream);
  hipMemsetAsync(ssum, 0, sizeof(float), stream);

  k_codebook<<<dim3(128, 4), 256, 0, stream>>>(emb, proj, cb, ef);
  k_norms   <<<32, 256, 0, stream>>>(cb, norms);
  k_prep_z  <<<512, 256, 0, stream>>>(z, zf, znorm);
  k_scan    <<<2048, 256, 0, stream>>>(zf, ef, norms, znorm,
                                       rowminG, rowcnt, slots);
  k_rescore <<<512, 256, 0, stream>>>(z, cb, norms, znorm,
                                      rowminG, rowcnt, slots, packed);
  k_output  <<<512, 256, 0, stream>>>(z, cb, packed, out, idxf, ssum);
  k_final   <<<1, 1, 0, stream>>>(ssum, scal);

  (void)in_sizes; (void)n_in; (void)out_size; (void)ws_size;
}

// Round 12
// 374.182 us; speedup vs baseline: 1.2425x; 1.2425x over previous
//
#include <hip/hip_runtime.h>
#include <cfloat>

// VQ forward, MI355X. z[16,256,32,32] f32, emb[8192,256] f32, proj[256,256] f32.
// N = 16384 rows, K = 8192 codes, D = 256.
// d_out (floats): out[4194304] | loss | commitment | codebook_loss | idx_as_float[16384]
//
// R17 (393): single-pass scan, running-threshold emission, score-carrying slots
//  (quant19(sc-zn)<<13|k), final-threshold-filtered exact rescore.
// R18 (387): A-resident + k_codebook float4 LDS reads. R19 (465, REVERTED):
//  async atomic exchange doubled emissions (WRITE 21->44 MB) — staleness
//  propagates through all 16 wave-streams/row; sync exchange restored.
// R20: DISTANCE-4 B REGISTER PIPELINE — the one structural change. R12-R19
//  all left the same constant untouched: distance-1 prefetch covers ~40 cyc
//  of MFMA against ~200-300 cyc L2 latency, so all 64 d32 steps expose ~200
//  cyc and 2 waves/SIMD can't fill it (MfmaUtil+VALUBusy ~= 32% == 2 x
//  compute/(compute+stall)). Now Bq[4][4] stages (64 VGPR): consume stage
//  d32&3, refill same stage with step s+4 (static addresses after unroll;
//  compiler emits counted vmcnt(12)). Coverage 4 steps ~= 240 cyc >= L2.
//  Per-kt __syncthreads REMOVED: it drains vmcnt(0) (R9 lesson), killing the
//  kt-spanning pipeline; k_scan shares no LDS between waves -> removal safe.
//  Reg budget: A 64 + Bq 64 + acc 32(AGPR) + misc ~30 ~= 190 unified, fits
//  (256,2) (R15: never cap below the live set). Spill falsifier: WRITE jump.

constexpr int Dd = 256;
constexpr float INV_M = 1.0f / 4194304.0f;
constexpr float DLT = 8e-4f;
constexpr int SLOTS = 128;

typedef unsigned short u16;
typedef unsigned int u32;
typedef __attribute__((ext_vector_type(8))) short short8;   // 8 bf16
typedef __attribute__((ext_vector_type(4))) float f32x4;

__device__ __forceinline__ unsigned monof(float f) {
  unsigned u = __float_as_uint(f);
  return (u & 0x80000000u) ? ~u : (u | 0x80000000u);
}
__device__ __forceinline__ float unmonof(unsigned p) {
  unsigned u = (p & 0x80000000u) ? (p & 0x7FFFFFFFu) : ~p;
  return __uint_as_float(u);
}
__device__ __forceinline__ u16 f2bf(float x) {   // RNE float->bf16 bits
  unsigned u = __float_as_uint(x);
  u += 0x7FFFu + ((u >> 16) & 1u);
  return (u16)(u >> 16);
}

// ---- K1: codebook = emb @ proj^T -> cb[k][d] fp32 + ef bf16 fragment-order ----
__global__ __launch_bounds__(256)
void k_codebook(const float* __restrict__ emb, const float* __restrict__ proj,
                float* __restrict__ cb, u16* __restrict__ ef) {
  __shared__ __align__(16) float et[64 * 68];
  __shared__ __align__(16) float pt[64 * 68];
  __shared__ __align__(16) u16 tileT[64 * 72];
  const int t = threadIdx.x;
  const int tx = t & 15, ty = t >> 4;
  const int kb = blockIdx.x * 64;
  const int db = blockIdx.y * 64;
  float acc[4][4];
#pragma unroll
  for (int u = 0; u < 4; ++u)
#pragma unroll
    for (int v = 0; v < 4; ++v) acc[u][v] = 0.f;

  const int jm = t & 15;
  const int q  = t >> 4;

  for (int jc = 0; jc < Dd; jc += 64) {
    __syncthreads();
#pragma unroll
    for (int i = 0; i < 4; ++i) {
      const int row = q + i * 16;
      const float4 e4 = *(const float4*)(emb  + (size_t)(kb + row) * Dd + jc + jm * 4);
      const float4 p4 = *(const float4*)(proj + (size_t)(db + row) * Dd + jc + jm * 4);
      et[(jm*4 + 0) * 68 + row] = e4.x;
      et[(jm*4 + 1) * 68 + row] = e4.y;
      et[(jm*4 + 2) * 68 + row] = e4.z;
      et[(jm*4 + 3) * 68 + row] = e4.w;
      pt[(jm*4 + 0) * 68 + row] = p4.x;
      pt[(jm*4 + 1) * 68 + row] = p4.y;
      pt[(jm*4 + 2) * 68 + row] = p4.z;
      pt[(jm*4 + 3) * 68 + row] = p4.w;
    }
    __syncthreads();
#pragma unroll 16
    for (int j = 0; j < 64; ++j) {
      const float4 a4 = *(const float4*)(et + j * 68 + ty * 4);
      const float4 b4 = *(const float4*)(pt + j * 68 + tx * 4);
      const float a[4] = {a4.x, a4.y, a4.z, a4.w};
      const float b[4] = {b4.x, b4.y, b4.z, b4.w};
#pragma unroll
      for (int u = 0; u < 4; ++u)
#pragma unroll
        for (int v = 0; v < 4; ++v) acc[u][v] = fmaf(a[u], b[v], acc[u][v]);
    }
  }
  // fp32 cb (linear) + bf16 tile to LDS for fragment-order shuffle
#pragma unroll
  for (int u = 0; u < 4; ++u) {
    const int k = kb + ty*4 + u;
#pragma unroll
    for (int v = 0; v < 4; ++v) {
      const int d = db + tx*4 + v;
      const float val = acc[u][v];
      cb[(size_t)k * Dd + d] = val;
      tileT[(ty*4 + u) * 72 + tx*4 + v] = f2bf(val);
    }
  }
  __syncthreads();
  // emit 512 fragment granules (16 B each), coalesced
  uint4* ef16 = (uint4*)ef;
#pragma unroll
  for (int w2 = 0; w2 < 2; ++w2) {
    const int uu = w2 * 256 + t;
    const int k16g = uu >> 7;            // 0..3 (16-k group within tile)
    const int d32g = (uu >> 6) & 1;      // 0..1 (32-d group within tile)
    const int ln   = uu & 63;            // fragment lane
    const int klo  = k16g * 16 + (ln & 15);
    const int dlo  = d32g * 32 + (ln >> 4) * 8;
    ef16[((kb >> 4) + k16g) * 512 + ((db >> 5) + d32g) * 64 + ln] =
        *(const uint4*)&tileT[klo * 72 + dlo];
  }
}

// ---- K1b: per-code norms (ascending-d fmaf chain) ----
__global__ __launch_bounds__(256)
void k_norms(const float* __restrict__ cb, float* __restrict__ norms) {
  const int k = blockIdx.x * 256 + threadIdx.x;
  const float* row = cb + (size_t)k * Dd;
  float s = 0.f;
  for (int d = 0; d < Dd; d += 4) {
    const float4 v = *(const float4*)(row + d);
    s = fmaf(v.x, v.x, s);
    s = fmaf(v.y, v.y, s);
    s = fmaf(v.z, v.z, s);
    s = fmaf(v.w, v.w, s);
  }
  norms[k] = s;
}

// ---- K1c: transpose z -> zf bf16 fragment-order + znorm ----
__global__ __launch_bounds__(256)
void k_prep_z(const float* __restrict__ z, u16* __restrict__ zf,
              float* __restrict__ znorm) {
  __shared__ float tile[256 * 33];
  const int t = threadIdx.x;
  const int blk = blockIdx.x;            // b*32 + h
  const int w = t & 31, rg = t >> 5;
  const size_t zbase = (size_t)(blk >> 5) * 262144 + (size_t)(blk & 31) * 32 + w;
#pragma unroll 8
  for (int i = 0; i < 32; ++i) {
    const int d = rg * 32 + i;
    tile[d * 33 + w] = z[zbase + (size_t)d * 1024];
  }
  __syncthreads();
  if (t < 32) {
    float s = 0.f;
    for (int d = 0; d < Dd; ++d) {
      const float v = tile[d * 33 + t];
      s = fmaf(v, v, s);
    }
    znorm[blk * 32 + t] = s;
  }
  // fragment-order write: granule U = ((n>>4)*8 + d32)*64 + qd*16 + (n&15)
  const int ml16 = t & 15;
  const int seg  = (t >> 4) & 7;         // d32 group
  const int hi   = t >> 7;               // n16 group within block (0/1)
  const int nl   = hi * 16 + ml16;       // row 0..31 within block
  uint4* zf16 = (uint4*)zf;
  const int ubase = ((blk * 2 + hi) * 8 + seg) * 64 + ml16;
#pragma unroll
  for (int j = 0; j < 4; ++j) {          // qd octet
    u16 hb[8];
#pragma unroll
    for (int e = 0; e < 8; ++e)
      hb[e] = f2bf(tile[(seg * 32 + j * 8 + e) * 33 + nl]);
    zf16[ubase + j * 16] = *(const uint4*)hb;
  }
}

// ---- K2: single-pass MFMA scan, distance-4 B register pipeline ----
// Block 64 rows x 1024 cols; wave (rowhalf,colhalf) = 32 rows x 128 cols.
// No LDS, no barriers; compiler-counted vmcnt(12) steady state.
__global__ __launch_bounds__(256, 2)
void k_scan(const u16* __restrict__ zf, const u16* __restrict__ ef,
            const float* __restrict__ norms, const float* __restrict__ znorm,
            u32* __restrict__ rowminG, u32* __restrict__ rowcnt,
            u32* __restrict__ slots) {
  const int t    = threadIdx.x;
  const int lane = t & 63;
  const int ml   = lane & 15;
  const int qd   = lane >> 4;
  const int wvu  = __builtin_amdgcn_readfirstlane(t >> 6);
  const int rowhalf = wvu & 1;           // 0/1 -> 32 rows
  const int colhalf = wvu >> 1;          // 0/1 -> 128 cols (of kt's 256)
  const int bid  = blockIdx.x;
  const int kb   = (bid & 7) * 1024;     // colgroup -> XCD-local ef reuse
  const int nb   = (bid >> 3) * 64;

  const uint4* zf16 = (const uint4*)zf;
  const uint4* ef16 = (const uint4*)ef;
  // B granule (kt,cq,ct,d32): eb + ((kt*16)+(cq*4)+ct)*512 + d32*64
  const uint4* eb = ef16 + (size_t)((kb >> 4) + colhalf * 8) * 512 + lane;

  // ---- A resident in VGPR: A[rt][d32], 16 granules = 64 VGPR, loaded once ----
  short8 A[2][8];
  {
    const uint4* za = zf16 + (size_t)((nb >> 4) + rowhalf * 2) * 512 + lane;
#pragma unroll
    for (int rt = 0; rt < 2; ++rt)
#pragma unroll
      for (int d32 = 0; d32 < 8; ++d32)
        A[rt][d32] = *(const short8*)(za + rt * 512 + d32 * 64);
  }

  // per-thread rows: n = nb + rowhalf*32 + rt*16 + qd*4 + r
  float zn[2][4];
#pragma unroll
  for (int rt = 0; rt < 2; ++rt) {
    const int nr = nb + rowhalf * 32 + rt * 16 + qd * 4;
    const f32x4 z4 = *(const f32x4*)(znorm + nr);
#pragma unroll
    for (int r = 0; r < 4; ++r) zn[rt][r] = z4[r];
  }

  // ---- B pipeline: 4 stages x 4 ct granules; stage = d32&3 (static) ----
  short8 Bq[4][4];
#pragma unroll
  for (int s = 0; s < 4; ++s)            // prologue: steps 0..3 (kt=0,cq=0)
#pragma unroll
    for (int ct = 0; ct < 4; ++ct)
      Bq[s][ct] = *(const short8*)(eb + ct * 512 + s * 64);

#pragma unroll 1
  for (int kt = 0; kt < 4; ++kt) {
    const size_t ekt = (size_t)kt * 16 * 512;
#pragma unroll
    for (int cq = 0; cq < 2; ++cq) {
      const uint4* ecq = eb + ekt + (size_t)(cq * 4) * 512;

      f32x4 acc[2][4];
#pragma unroll
      for (int rt = 0; rt < 2; ++rt)
#pragma unroll
        for (int ct = 0; ct < 4; ++ct) acc[rt][ct] = (f32x4)0.f;

#pragma unroll
      for (int d32 = 0; d32 < 8; ++d32) {
        const int st = d32 & 3;
        // consume stage st (loads issued 4 steps ago -> vmcnt(12) wait)
#pragma unroll
        for (int ct = 0; ct < 4; ++ct)
#pragma unroll
          for (int rt = 0; rt < 2; ++rt)
            acc[rt][ct] = __builtin_amdgcn_mfma_f32_16x16x32_bf16(
                A[rt][d32], Bq[st][ct], acc[rt][ct], 0, 0, 0);
        // refill stage st with step s+4 (same quad / next quad / next kt)
        const bool last4 = (kt == 3) && (cq == 1) && (d32 >= 4);
        if (!last4) {
          const uint4* pn;
          if (d32 < 4) {
            pn = ecq + (d32 + 4) * 64;                       // same quad
          } else if (cq == 0) {
            pn = eb + ekt + (size_t)4 * 512 + (d32 - 4) * 64;   // quad cq=1
          } else {
            pn = eb + ekt + (size_t)16 * 512 + (d32 - 4) * 64;  // next kt, cq=0
          }
#pragma unroll
          for (int ct = 0; ct < 4; ++ct)
            Bq[st][ct] = *(const short8*)(pn + ct * 512);
        }
      }

      // ---- scores in place: acc = (zn + nk) - 2*acc  (quantized fold) ----
#pragma unroll
      for (int ct = 0; ct < 4; ++ct) {
        const int k0 = kb + kt * 256 + colhalf * 128 + cq * 64 + ct * 16 + ml;
        const float nkv = norms[k0];
#pragma unroll
        for (int rt = 0; rt < 2; ++rt)
#pragma unroll
          for (int r = 0; r < 4; ++r)
            acc[rt][ct][r] = (zn[rt][r] + nkv) - 2.0f * acc[rt][ct][r];
      }

      // ---- per-row quad min (over ct, then over 16 ml lanes) ----
      float m2[2][4];
#pragma unroll
      for (int rt = 0; rt < 2; ++rt)
#pragma unroll
        for (int r = 0; r < 4; ++r) {
          float m = fminf(fminf(acc[rt][0][r], acc[rt][1][r]),
                          fminf(acc[rt][2][r], acc[rt][3][r]));
#pragma unroll
          for (int s = 1; s < 16; s <<= 1) m = fminf(m, __shfl_xor(m, s, 64));
          m2[rt][r] = m;
        }

      // ---- sync atomicMin exchange (R18 form: freshest threshold) ----
      unsigned myg = 0xFFFFFFFFu;
      if (ml < 8) {
        const int rt_ = ml >> 2, r_ = ml & 3;
        const int n = nb + rowhalf * 32 + rt_ * 16 + qd * 4 + r_;
        const unsigned pk = monof(m2[rt_][r_]);
        const unsigned old = atomicMin(&rowminG[n], pk);
        myg = min(old, pk);
      }
      float thrv[2][4];
#pragma unroll
      for (int rt = 0; rt < 2; ++rt)
#pragma unroll
        for (int r = 0; r < 4; ++r) {
          const unsigned gg = __shfl(myg, (lane & 48) + rt * 4 + r, 64);
          thrv[rt][r] = unmonof(gg) + DLT;
        }

      // ---- emit candidates: sc <= freshest-global-min + DLT ----
      // slot payload: quant19(sc - zn) << 13 | k  (Sterbenz-exact sc-zn, 2^-21 res)
#pragma unroll
      for (int ct = 0; ct < 4; ++ct) {
        const int k = kb + kt * 256 + colhalf * 128 + cq * 64 + ct * 16 + ml;
#pragma unroll
        for (int rt = 0; rt < 2; ++rt)
#pragma unroll
          for (int r = 0; r < 4; ++r) {
            if (acc[rt][ct][r] <= thrv[rt][r]) {
              const int n = nb + rowhalf * 32 + rt * 16 + qd * 4 + r;
              const u32 pos = atomicAdd(&rowcnt[n], 1u);
              if (pos < (u32)SLOTS) {
                const float e = acc[rt][ct][r] - zn[rt][r];
                int q = __float2int_rn(e * 2097152.0f) + 262144;
                q = q < 0 ? 0 : (q > 524287 ? 524287 : q);
                slots[n * SLOTS + pos] = ((u32)q << 13) | (u32)k;
              }
            }
          }
      }
    }
    // no __syncthreads: would drain vmcnt(0) and kill the kt-spanning pipeline;
    // k_scan shares nothing between waves except global atomics (order-free).
  }
}

// ---- K2c: filtered exact rescore (full-scan fallback on overflow) ----
// Block per (b,h): 32 rows; LDS z-tile [32][261] fp32; wave per 8 rows.
__global__ __launch_bounds__(256)
void k_rescore(const float* __restrict__ z, const float* __restrict__ cb,
               const float* __restrict__ norms, const float* __restrict__ znorm,
               const u32* __restrict__ rowminG, const u32* __restrict__ rowcnt,
               const u32* __restrict__ slots,
               unsigned long long* __restrict__ packed) {
  __shared__ float ztl[32 * 261];
  const int t = threadIdx.x;
  const int blk = blockIdx.x;          // b*32 + h
  const int w = t & 31, dg = t >> 5;
  const size_t zbase = (size_t)(blk >> 5) * 262144 + (size_t)(blk & 31) * 32;
#pragma unroll 8
  for (int i = 0; i < 32; ++i) {
    const int d = dg * 32 + i;
    ztl[w * 261 + d] = z[zbase + (size_t)d * 1024 + w];
  }
  __syncthreads();

  const int lane = t & 63;
  const int wv = t >> 6;               // 4 waves
  // 4 waves x 8 rows each
#pragma unroll 1
  for (int i = 0; i < 8; ++i) {
    const int rl = wv * 8 + i;
    const int n = blk * 32 + rl;
    const u32 cnt = rowcnt[n];
    const float znr = znorm[n];
    const float* zp = ztl + rl * 261 + lane * 4;
    // final-threshold filter in encoded domain (+68 LSB covers all rounding)
    const float g = unmonof(rowminG[n]);
    const int qThr = __float2int_rn((g + DLT - znr) * 2097152.0f) + 262144 + 68;
    unsigned long long best = 0xFFFFFFFFFFFFFFFFull;
    if (cnt <= (u32)SLOTS) {
      for (u32 c = 0; c < cnt; ++c) {
        const u32 v = slots[n * SLOTS + c];      // wave-uniform addr -> broadcast
        if ((int)(v >> 13) > qThr) continue;     // uniform branch
        const int k = (int)(v & 8191u);
        const float4 c4 = *(const float4*)(cb + (size_t)k * Dd + lane * 4);
        float p = 0.f;
        p = fmaf(zp[0], c4.x, p);
        p = fmaf(zp[1], c4.y, p);
        p = fmaf(zp[2], c4.z, p);
        p = fmaf(zp[3], c4.w, p);
#pragma unroll
        for (int s = 1; s < 64; s <<= 1) p += __shfl_xor(p, s, 64);
        const float sc = (znr + norms[k]) - 2.0f * p;   // quantized fold
        const unsigned long long pk =
            ((unsigned long long)monof(sc) << 32) | (unsigned)k;
        if (pk < best) best = pk;                        // ties -> min k
      }
    } else {
      // overflow fallback (never expected): exact scan of all 8192 codes
      for (int k = 0; k < 8192; ++k) {
        const float4 c4 = *(const float4*)(cb + (size_t)k * Dd + lane * 4);
        float p = 0.f;
        p = fmaf(zp[0], c4.x, p);
        p = fmaf(zp[1], c4.y, p);
        p = fmaf(zp[2], c4.z, p);
        p = fmaf(zp[3], c4.w, p);
#pragma unroll
        for (int s = 1; s < 64; s <<= 1) p += __shfl_xor(p, s, 64);
        const float sc = (znr + norms[k]) - 2.0f * p;
        const unsigned long long pk =
            ((unsigned long long)monof(sc) << 32) | (unsigned)k;
        if (pk < best) best = pk;
      }
    }
    if (lane == 0 && cnt > 0) packed[n] = best;
  }
}

// ---- K3: gather codes, write out (NCHW), idx floats, reduce SSE ----
__global__ __launch_bounds__(256)
void k_output(const float* __restrict__ z, const float* __restrict__ cb,
              const unsigned long long* __restrict__ packed,
              float* __restrict__ out, float* __restrict__ idxf,
              float* __restrict__ ssum) {
  __shared__ float zqT[256 * 33];
  __shared__ float part[4];
  const int t = threadIdx.x;
  const int blk = blockIdx.x;       // = b*32 + h
  const int nbase = blk * 32;

  {
    const int nl = t >> 3, m = t & 7;
    // guard the GATHER address only (&8191): if upstream ever leaves the
    // sentinel, we return wrong values (checker catches) instead of faulting.
    const int idx = (int)(packed[nbase + nl] & 0xFFFFFFFFull) & 8191;
    const float* row = cb + (size_t)idx * Dd;
#pragma unroll
    for (int i = 0; i < 8; ++i) {
      const int d0 = m * 4 + i * 32;
      const float4 v = *(const float4*)(row + d0);
      zqT[(d0 + 0) * 33 + nl] = v.x;
      zqT[(d0 + 1) * 33 + nl] = v.y;
      zqT[(d0 + 2) * 33 + nl] = v.z;
      zqT[(d0 + 3) * 33 + nl] = v.w;
    }
    if (t < 32)
      idxf[nbase + t] = (float)(unsigned)(packed[nbase + t] & 0xFFFFFFFFull);
  }
  __syncthreads();

  const int w = t & 31, cg = t >> 5;
  const size_t base = (size_t)(blk >> 5) * 262144 + (size_t)(blk & 31) * 32 + w;
  float local = 0.f;
#pragma unroll
  for (int cc = 0; cc < 32; ++cc) {
    const int c = cg * 32 + cc;
    const float q  = zqT[c * 33 + w];
    const float zv = z[base + (size_t)c * 1024];
    out[base + (size_t)c * 1024] = q;
    const float dd = q - zv;
    local = fmaf(dd, dd, local);
  }
  float v = local;
#pragma unroll
  for (int m = 1; m < 64; m <<= 1) v += __shfl_xor(v, m, 64);
  if ((t & 63) == 0) part[t >> 6] = v;
  __syncthreads();
  if (t == 0) atomicAdd(ssum, part[0] + part[1] + part[2] + part[3]);
}

// ---- K4: finalize scalars ----
__global__ void k_final(const float* __restrict__ ssum, float* __restrict__ scal) {
  const float m = *ssum * INV_M;
  scal[0] = 1.25f * m;   // loss
  scal[1] = 0.25f * m;   // commitment_loss
  scal[2] = m;           // codebook_loss
}

extern "C" void kernel_launch(void* const* d_in, const int* in_sizes, int n_in,
                              void* d_out, int out_size, void* d_ws, size_t ws_size,
                              hipStream_t stream) {
  const float* z    = (const float*)d_in[0];
  const float* emb  = (const float*)d_in[1];
  const float* proj = (const float*)d_in[2];

  float* out  = (float*)d_out;
  float* scal = out + 4194304;
  float* idxf = out + 4194307;

  // ws (~28.9 MB): cb | norms | packed | znorm | zf | ef | rowminG | rowcnt | slots(u32) | ssum
  float* cb    = (float*)d_ws;                          // 8 MB
  float* norms = cb + 2097152;                          // 32 KB
  unsigned long long* packed =
      (unsigned long long*)(norms + 8192);              // 128 KB
  float* znorm = (float*)(packed + 16384);              // 64 KB
  u16* zf = (u16*)(znorm + 16384);                      // 8.4 MB (fragment-order)
  u16* ef = zf + 4194304;                               // 4.2 MB (fragment-order)
  u32* rowminG = (u32*)(ef + 2097152);                  // 64 KB
  u32* rowcnt = rowminG + 16384;                        // 64 KB
  u32* slots = rowcnt + 16384;                          // 8 MB (128 u32/row)
  float* ssum = (float*)(slots + (size_t)16384 * SLOTS);// 4 B

  hipMemsetAsync(rowminG, 0xFF, 16384 * sizeof(u32), stream);
  hipMemsetAsync(rowcnt, 0, 16384 * sizeof(u32), stream);
  hipMemsetAsync(packed, 0xFF, 16384 * sizeof(unsigned long long), stream);
  hipMemsetAsync(ssum, 0, sizeof(float), stream);

  k_codebook<<<dim3(128, 4), 256, 0, stream>>>(emb, proj, cb, ef);
  k_norms   <<<32, 256, 0, stream>>>(cb, norms);
  k_prep_z  <<<512, 256, 0, stream>>>(z, zf, znorm);
  k_scan    <<<2048, 256, 0, stream>>>(zf, ef, norms, znorm,
                                       rowminG, rowcnt, slots);
  k_rescore <<<512, 256, 0, stream>>>(z, cb, norms, znorm,
                                      rowminG, rowcnt, slots, packed);
  k_output  <<<512, 256, 0, stream>>>(z, cb, packed, out, idxf, ssum);
  k_final   <<<1, 1, 0, stream>>>(ssum, scal);

  (void)in_sizes; (void)n_in; (void)out_size; (void)ws_size;
}

// Round 13
// 361.905 us; speedup vs baseline: 1.2847x; 1.0339x over previous
//
#include <hip/hip_runtime.h>
#include <cfloat>

// VQ forward, MI355X. z[16,256,32,32] f32, emb[8192,256] f32, proj[256,256] f32.
// N = 16384 rows, K = 8192 codes, D = 256.
// d_out (floats): out[4194304] | loss | commitment | codebook_loss | idx_as_float[16384]
//
// R17 (393): single-pass scan, running-threshold emission, score-carrying slots
//  (quant19(sc-zn)<<13|k), final-threshold-filtered exact rescore.
// R18 (387): A-resident + k_codebook float4. R19 (REVERTED): async exchange
//  doubled emissions. R20 (374): distance-4 B pipeline, no in-loop barriers.
// R21: OCCUPANCY x2 — A moves from 64 VGPRs to a 32 KB LDS tile.
//  R20's counters: MfmaUtil+VALUBusy ~35% at ~152 unified regs = the 129-256
//  bracket's 2 waves/SIMD cap. Pipelining at fixed occupancy is exhausted
//  (199->190 over 5 rounds); the stall needs more resident waves.
//   - A tile is CONTIGUOUS in fragment order -> staged once via global_load_lds
//     (linear dest), ONE barrier, then READ-ONLY: no WAR race possible (unlike
//     R13/R14's in-loop staging). Per step: 2 stride-1 ds_read_b128 (conflict-
//     free), double-buffered 1 step ahead (compile-time indices).
//   - B pipeline distance-2 (parity d32&1, compile-time under runtime kt):
//     at 4 waves/SIMD the wall issue-to-use gap is ~4x own-wave -> covers L2.
//   - __launch_bounds__(256,4): caps 128 regs; live set ~105 (Bb32+acc32+As16+
//     zn8+temps) — headroom, unlike R15's 180-under-128 spill disaster.
//     LDS 32KB x 4 blocks = 128 <= 160 KB. Spill falsifier: WRITE_SIZE jump.
//  Sync atomicMin exchange retained (R19 lesson: staleness doubles emissions).

constexpr int Dd = 256;
constexpr float INV_M = 1.0f / 4194304.0f;
constexpr float DLT = 8e-4f;
constexpr int SLOTS = 128;

typedef unsigned short u16;
typedef unsigned int u32;
typedef __attribute__((ext_vector_type(8))) short short8;   // 8 bf16
typedef __attribute__((ext_vector_type(4))) float f32x4;

#define GLOBAL_AS __attribute__((address_space(1)))
#define LDS_AS    __attribute__((address_space(3)))

__device__ __forceinline__ unsigned monof(float f) {
  unsigned u = __float_as_uint(f);
  return (u & 0x80000000u) ? ~u : (u | 0x80000000u);
}
__device__ __forceinline__ float unmonof(unsigned p) {
  unsigned u = (p & 0x80000000u) ? (p & 0x7FFFFFFFu) : ~p;
  return __uint_as_float(u);
}
__device__ __forceinline__ u16 f2bf(float x) {   // RNE float->bf16 bits
  unsigned u = __float_as_uint(x);
  u += 0x7FFFu + ((u >> 16) & 1u);
  return (u16)(u >> 16);
}

// ---- K1: codebook = emb @ proj^T -> cb[k][d] fp32 + ef bf16 fragment-order ----
__global__ __launch_bounds__(256)
void k_codebook(const float* __restrict__ emb, const float* __restrict__ proj,
                float* __restrict__ cb, u16* __restrict__ ef) {
  __shared__ __align__(16) float et[64 * 68];
  __shared__ __align__(16) float pt[64 * 68];
  __shared__ __align__(16) u16 tileT[64 * 72];
  const int t = threadIdx.x;
  const int tx = t & 15, ty = t >> 4;
  const int kb = blockIdx.x * 64;
  const int db = blockIdx.y * 64;
  float acc[4][4];
#pragma unroll
  for (int u = 0; u < 4; ++u)
#pragma unroll
    for (int v = 0; v < 4; ++v) acc[u][v] = 0.f;

  const int jm = t & 15;
  const int q  = t >> 4;

  for (int jc = 0; jc < Dd; jc += 64) {
    __syncthreads();
#pragma unroll
    for (int i = 0; i < 4; ++i) {
      const int row = q + i * 16;
      const float4 e4 = *(const float4*)(emb  + (size_t)(kb + row) * Dd + jc + jm * 4);
      const float4 p4 = *(const float4*)(proj + (size_t)(db + row) * Dd + jc + jm * 4);
      et[(jm*4 + 0) * 68 + row] = e4.x;
      et[(jm*4 + 1) * 68 + row] = e4.y;
      et[(jm*4 + 2) * 68 + row] = e4.z;
      et[(jm*4 + 3) * 68 + row] = e4.w;
      pt[(jm*4 + 0) * 68 + row] = p4.x;
      pt[(jm*4 + 1) * 68 + row] = p4.y;
      pt[(jm*4 + 2) * 68 + row] = p4.z;
      pt[(jm*4 + 3) * 68 + row] = p4.w;
    }
    __syncthreads();
#pragma unroll 16
    for (int j = 0; j < 64; ++j) {
      const float4 a4 = *(const float4*)(et + j * 68 + ty * 4);
      const float4 b4 = *(const float4*)(pt + j * 68 + tx * 4);
      const float a[4] = {a4.x, a4.y, a4.z, a4.w};
      const float b[4] = {b4.x, b4.y, b4.z, b4.w};
#pragma unroll
      for (int u = 0; u < 4; ++u)
#pragma unroll
        for (int v = 0; v < 4; ++v) acc[u][v] = fmaf(a[u], b[v], acc[u][v]);
    }
  }
  // fp32 cb (linear) + bf16 tile to LDS for fragment-order shuffle
#pragma unroll
  for (int u = 0; u < 4; ++u) {
    const int k = kb + ty*4 + u;
#pragma unroll
    for (int v = 0; v < 4; ++v) {
      const int d = db + tx*4 + v;
      const float val = acc[u][v];
      cb[(size_t)k * Dd + d] = val;
      tileT[(ty*4 + u) * 72 + tx*4 + v] = f2bf(val);
    }
  }
  __syncthreads();
  // emit 512 fragment granules (16 B each), coalesced
  uint4* ef16 = (uint4*)ef;
#pragma unroll
  for (int w2 = 0; w2 < 2; ++w2) {
    const int uu = w2 * 256 + t;
    const int k16g = uu >> 7;            // 0..3 (16-k group within tile)
    const int d32g = (uu >> 6) & 1;      // 0..1 (32-d group within tile)
    const int ln   = uu & 63;            // fragment lane
    const int klo  = k16g * 16 + (ln & 15);
    const int dlo  = d32g * 32 + (ln >> 4) * 8;
    ef16[((kb >> 4) + k16g) * 512 + ((db >> 5) + d32g) * 64 + ln] =
        *(const uint4*)&tileT[klo * 72 + dlo];
  }
}

// ---- K1b: per-code norms (ascending-d fmaf chain) ----
__global__ __launch_bounds__(256)
void k_norms(const float* __restrict__ cb, float* __restrict__ norms) {
  const int k = blockIdx.x * 256 + threadIdx.x;
  const float* row = cb + (size_t)k * Dd;
  float s = 0.f;
  for (int d = 0; d < Dd; d += 4) {
    const float4 v = *(const float4*)(row + d);
    s = fmaf(v.x, v.x, s);
    s = fmaf(v.y, v.y, s);
    s = fmaf(v.z, v.z, s);
    s = fmaf(v.w, v.w, s);
  }
  norms[k] = s;
}

// ---- K1c: transpose z -> zf bf16 fragment-order + znorm ----
__global__ __launch_bounds__(256)
void k_prep_z(const float* __restrict__ z, u16* __restrict__ zf,
              float* __restrict__ znorm) {
  __shared__ float tile[256 * 33];
  const int t = threadIdx.x;
  const int blk = blockIdx.x;            // b*32 + h
  const int w = t & 31, rg = t >> 5;
  const size_t zbase = (size_t)(blk >> 5) * 262144 + (size_t)(blk & 31) * 32 + w;
#pragma unroll 8
  for (int i = 0; i < 32; ++i) {
    const int d = rg * 32 + i;
    tile[d * 33 + w] = z[zbase + (size_t)d * 1024];
  }
  __syncthreads();
  if (t < 32) {
    float s = 0.f;
    for (int d = 0; d < Dd; ++d) {
      const float v = tile[d * 33 + t];
      s = fmaf(v, v, s);
    }
    znorm[blk * 32 + t] = s;
  }
  // fragment-order write: granule U = ((n>>4)*8 + d32)*64 + qd*16 + (n&15)
  const int ml16 = t & 15;
  const int seg  = (t >> 4) & 7;         // d32 group
  const int hi   = t >> 7;               // n16 group within block (0/1)
  const int nl   = hi * 16 + ml16;       // row 0..31 within block
  uint4* zf16 = (uint4*)zf;
  const int ubase = ((blk * 2 + hi) * 8 + seg) * 64 + ml16;
#pragma unroll
  for (int j = 0; j < 4; ++j) {          // qd octet
    u16 hb[8];
#pragma unroll
    for (int e = 0; e < 8; ++e)
      hb[e] = f2bf(tile[(seg * 32 + j * 8 + e) * 33 + nl]);
    zf16[ubase + j * 16] = *(const uint4*)hb;
  }
}

// ---- K2: single-pass MFMA scan; A in LDS (staged once), B dist-2 reg pipe ----
// Block 64 rows x 1024 cols; wave (rowhalf,colhalf) = 32 rows x 128 cols.
// 4 blocks/CU target: regs <= 128, LDS 32 KB.
__global__ __launch_bounds__(256, 4)
void k_scan(const u16* __restrict__ zf, const u16* __restrict__ ef,
            const float* __restrict__ norms, const float* __restrict__ znorm,
            u32* __restrict__ rowminG, u32* __restrict__ rowcnt,
            u32* __restrict__ slots) {
  __shared__ __align__(16) u16 zsh[64 * 256];   // 32 KB A tile (fragment order)
  const int t    = threadIdx.x;
  const int lane = t & 63;
  const int ml   = lane & 15;
  const int qd   = lane >> 4;
  const int wvu  = __builtin_amdgcn_readfirstlane(t >> 6);
  const int rowhalf = wvu & 1;           // 0/1 -> 32 rows
  const int colhalf = wvu >> 1;          // 0/1 -> 128 cols (of kt's 256)
  const int bid  = blockIdx.x;
  const int kb   = (bid & 7) * 1024;     // colgroup -> XCD-local ef reuse
  const int nb   = (bid >> 3) * 64;

  const uint4* zf16 = (const uint4*)zf;
  const uint4* ef16 = (const uint4*)ef;

  // ---- stage A once: block rows are contiguous granules in fragment order ----
  {
    const uint4* zsrc = zf16 + (size_t)(nb >> 4) * 512;
#pragma unroll
    for (int i = 0; i < 8; ++i) {
      const int g = wvu * 512 + i * 64;    // wave's 8 x 1KB chunks
      __builtin_amdgcn_global_load_lds((const GLOBAL_AS void*)(zsrc + g + lane),
                                       (LDS_AS void*)(zsh + (size_t)g * 8), 16, 0, 0);
    }
  }
  __syncthreads();   // the ONLY barrier: A tile ready; LDS read-only hereafter

  // A granule (rt, d): u16 offset ((rowhalf*2+rt)*8 + d)*512 + lane*8 (stride-1)
  const u16* ab0 = zsh + (size_t)((rowhalf * 2 + 0) * 8) * 512 + lane * 8;
  const u16* ab1 = zsh + (size_t)((rowhalf * 2 + 1) * 8) * 512 + lane * 8;

  // B granule (kt,cq,ct,d32): eb + ((kt*16)+(cq*4)+ct)*512 + d32*64
  const uint4* eb = ef16 + (size_t)((kb >> 4) + colhalf * 8) * 512 + lane;

  // per-thread rows: n = nb + rowhalf*32 + rt*16 + qd*4 + r
  float zn[2][4];
#pragma unroll
  for (int rt = 0; rt < 2; ++rt) {
    const int nr = nb + rowhalf * 32 + rt * 16 + qd * 4;
    const f32x4 z4 = *(const f32x4*)(znorm + nr);
#pragma unroll
    for (int r = 0; r < 4; ++r) zn[rt][r] = z4[r];
  }

  // ---- A double buffer (1-step lookahead) + B distance-2 pipeline ----
  short8 As0[2], As1[2], Bb0[4], Bb1[4];
  As0[0] = *(const short8*)(ab0);            // d32 = 0
  As0[1] = *(const short8*)(ab1);
#pragma unroll
  for (int ct = 0; ct < 4; ++ct) {           // steps 0,1 (kt=0,cq=0)
    Bb0[ct] = *(const short8*)(eb + ct * 512);
    Bb1[ct] = *(const short8*)(eb + ct * 512 + 64);
  }

#pragma unroll 1
  for (int kt = 0; kt < 4; ++kt) {
    const size_t ekt = (size_t)kt * 16 * 512;
#pragma unroll
    for (int cq = 0; cq < 2; ++cq) {
      const uint4* ecq = eb + ekt + (size_t)(cq * 4) * 512;

      f32x4 acc[2][4];
#pragma unroll
      for (int rt = 0; rt < 2; ++rt)
#pragma unroll
        for (int ct = 0; ct < 4; ++ct) acc[rt][ct] = (f32x4)0.f;

#pragma unroll
      for (int d32 = 0; d32 < 8; ++d32) {
        // A prefetch: next step's granule into the OTHER parity buffer.
        // A depends only on d32 -> (d32+1)&7 is correct across quad bounds.
        const int dn = (d32 + 1) & 7;
        if (d32 & 1) {
          As0[0] = *(const short8*)(ab0 + dn * 512);
          As0[1] = *(const short8*)(ab1 + dn * 512);
        } else {
          As1[0] = *(const short8*)(ab0 + dn * 512);
          As1[1] = *(const short8*)(ab1 + dn * 512);
        }
        // consume parity d32&1
        if (d32 & 1) {
#pragma unroll
          for (int ct = 0; ct < 4; ++ct)
#pragma unroll
            for (int rt = 0; rt < 2; ++rt)
              acc[rt][ct] = __builtin_amdgcn_mfma_f32_16x16x32_bf16(
                  As1[rt], Bb1[ct], acc[rt][ct], 0, 0, 0);
        } else {
#pragma unroll
          for (int ct = 0; ct < 4; ++ct)
#pragma unroll
            for (int rt = 0; rt < 2; ++rt)
              acc[rt][ct] = __builtin_amdgcn_mfma_f32_16x16x32_bf16(
                  As0[rt], Bb0[ct], acc[rt][ct], 0, 0, 0);
        }
        // B refill: step s+2 into the SAME parity buffer (after consumption)
        const bool lastB = (kt == 3) && (cq == 1) && (d32 >= 6);
        if (!lastB) {
          const uint4* pn;
          if (d32 < 6) {
            pn = ecq + (d32 + 2) * 64;                          // same quad
          } else if (cq == 0) {
            pn = eb + ekt + (size_t)4 * 512 + (d32 - 6) * 64;   // quad cq=1
          } else {
            pn = eb + ekt + (size_t)16 * 512 + (d32 - 6) * 64;  // next kt, cq=0
          }
          if (d32 & 1) {
#pragma unroll
            for (int ct = 0; ct < 4; ++ct)
              Bb1[ct] = *(const short8*)(pn + ct * 512);
          } else {
#pragma unroll
            for (int ct = 0; ct < 4; ++ct)
              Bb0[ct] = *(const short8*)(pn + ct * 512);
          }
        }
      }

      // ---- scores in place: acc = (zn + nk) - 2*acc  (quantized fold) ----
#pragma unroll
      for (int ct = 0; ct < 4; ++ct) {
        const int k0 = kb + kt * 256 + colhalf * 128 + cq * 64 + ct * 16 + ml;
        const float nkv = norms[k0];
#pragma unroll
        for (int rt = 0; rt < 2; ++rt)
#pragma unroll
          for (int r = 0; r < 4; ++r)
            acc[rt][ct][r] = (zn[rt][r] + nkv) - 2.0f * acc[rt][ct][r];
      }

      // ---- per-row quad min (over ct, then over 16 ml lanes) ----
      float m2[2][4];
#pragma unroll
      for (int rt = 0; rt < 2; ++rt)
#pragma unroll
        for (int r = 0; r < 4; ++r) {
          float m = fminf(fminf(acc[rt][0][r], acc[rt][1][r]),
                          fminf(acc[rt][2][r], acc[rt][3][r]));
#pragma unroll
          for (int s = 1; s < 16; s <<= 1) m = fminf(m, __shfl_xor(m, s, 64));
          m2[rt][r] = m;
        }

      // ---- sync atomicMin exchange (freshest threshold; R19 lesson) ----
      unsigned myg = 0xFFFFFFFFu;
      if (ml < 8) {
        const int rt_ = ml >> 2, r_ = ml & 3;
        const int n = nb + rowhalf * 32 + rt_ * 16 + qd * 4 + r_;
        const unsigned pk = monof(m2[rt_][r_]);
        const unsigned old = atomicMin(&rowminG[n], pk);
        myg = min(old, pk);
      }
      float thrv[2][4];
#pragma unroll
      for (int rt = 0; rt < 2; ++rt)
#pragma unroll
        for (int r = 0; r < 4; ++r) {
          const unsigned gg = __shfl(myg, (lane & 48) + rt * 4 + r, 64);
          thrv[rt][r] = unmonof(gg) + DLT;
        }

      // ---- emit candidates: sc <= freshest-global-min + DLT ----
      // slot payload: quant19(sc - zn) << 13 | k  (Sterbenz-exact sc-zn, 2^-21 res)
#pragma unroll
      for (int ct = 0; ct < 4; ++ct) {
        const int k = kb + kt * 256 + colhalf * 128 + cq * 64 + ct * 16 + ml;
#pragma unroll
        for (int rt = 0; rt < 2; ++rt)
#pragma unroll
          for (int r = 0; r < 4; ++r) {
            if (acc[rt][ct][r] <= thrv[rt][r]) {
              const int n = nb + rowhalf * 32 + rt * 16 + qd * 4 + r;
              const u32 pos = atomicAdd(&rowcnt[n], 1u);
              if (pos < (u32)SLOTS) {
                const float e = acc[rt][ct][r] - zn[rt][r];
                int q = __float2int_rn(e * 2097152.0f) + 262144;
                q = q < 0 ? 0 : (q > 524287 ? 524287 : q);
                slots[n * SLOTS + pos] = ((u32)q << 13) | (u32)k;
              }
            }
          }
      }
    }
    // no __syncthreads: LDS is read-only after staging; pipelines span quads.
  }
}

// ---- K2c: filtered exact rescore (full-scan fallback on overflow) ----
// Block per (b,h): 32 rows; LDS z-tile [32][261] fp32; wave per 8 rows.
__global__ __launch_bounds__(256)
void k_rescore(const float* __restrict__ z, const float* __restrict__ cb,
               const float* __restrict__ norms, const float* __restrict__ znorm,
               const u32* __restrict__ rowminG, const u32* __restrict__ rowcnt,
               const u32* __restrict__ slots,
               unsigned long long* __restrict__ packed) {
  __shared__ float ztl[32 * 261];
  const int t = threadIdx.x;
  const int blk = blockIdx.x;          // b*32 + h
  const int w = t & 31, dg = t >> 5;
  const size_t zbase = (size_t)(blk >> 5) * 262144 + (size_t)(blk & 31) * 32;
#pragma unroll 8
  for (int i = 0; i < 32; ++i) {
    const int d = dg * 32 + i;
    ztl[w * 261 + d] = z[zbase + (size_t)d * 1024 + w];
  }
  __syncthreads();

  const int lane = t & 63;
  const int wv = t >> 6;               // 4 waves
  // 4 waves x 8 rows each
#pragma unroll 1
  for (int i = 0; i < 8; ++i) {
    const int rl = wv * 8 + i;
    const int n = blk * 32 + rl;
    const u32 cnt = rowcnt[n];
    const float znr = znorm[n];
    const float* zp = ztl + rl * 261 + lane * 4;
    // final-threshold filter in encoded domain (+68 LSB covers all rounding)
    const float g = unmonof(rowminG[n]);
    const int qThr = __float2int_rn((g + DLT - znr) * 2097152.0f) + 262144 + 68;
    unsigned long long best = 0xFFFFFFFFFFFFFFFFull;
    if (cnt <= (u32)SLOTS) {
      for (u32 c = 0; c < cnt; ++c) {
        const u32 v = slots[n * SLOTS + c];      // wave-uniform addr -> broadcast
        if ((int)(v >> 13) > qThr) continue;     // uniform branch
        const int k = (int)(v & 8191u);
        const float4 c4 = *(const float4*)(cb + (size_t)k * Dd + lane * 4);
        float p = 0.f;
        p = fmaf(zp[0], c4.x, p);
        p = fmaf(zp[1], c4.y, p);
        p = fmaf(zp[2], c4.z, p);
        p = fmaf(zp[3], c4.w, p);
#pragma unroll
        for (int s = 1; s < 64; s <<= 1) p += __shfl_xor(p, s, 64);
        const float sc = (znr + norms[k]) - 2.0f * p;   // quantized fold
        const unsigned long long pk =
            ((unsigned long long)monof(sc) << 32) | (unsigned)k;
        if (pk < best) best = pk;                        // ties -> min k
      }
    } else {
      // overflow fallback (never expected): exact scan of all 8192 codes
      for (int k = 0; k < 8192; ++k) {
        const float4 c4 = *(const float4*)(cb + (size_t)k * Dd + lane * 4);
        float p = 0.f;
        p = fmaf(zp[0], c4.x, p);
        p = fmaf(zp[1], c4.y, p);
        p = fmaf(zp[2], c4.z, p);
        p = fmaf(zp[3], c4.w, p);
#pragma unroll
        for (int s = 1; s < 64; s <<= 1) p += __shfl_xor(p, s, 64);
        const float sc = (znr + norms[k]) - 2.0f * p;
        const unsigned long long pk =
            ((unsigned long long)monof(sc) << 32) | (unsigned)k;
        if (pk < best) best = pk;
      }
    }
    if (lane == 0 && cnt > 0) packed[n] = best;
  }
}

// ---- K3: gather codes, write out (NCHW), idx floats, reduce SSE ----
__global__ __launch_bounds__(256)
void k_output(const float* __restrict__ z, const float* __restrict__ cb,
              const unsigned long long* __restrict__ packed,
              float* __restrict__ out, float* __restrict__ idxf,
              float* __restrict__ ssum) {
  __shared__ float zqT[256 * 33];
  __shared__ float part[4];
  const int t = threadIdx.x;
  const int blk = blockIdx.x;       // = b*32 + h
  const int nbase = blk * 32;

  {
    const int nl = t >> 3, m = t & 7;
    // guard the GATHER address only (&8191): if upstream ever leaves the
    // sentinel, we return wrong values (checker catches) instead of faulting.
    const int idx = (int)(packed[nbase + nl] & 0xFFFFFFFFull) & 8191;
    const float* row = cb + (size_t)idx * Dd;
#pragma unroll
    for (int i = 0; i < 8; ++i) {
      const int d0 = m * 4 + i * 32;
      const float4 v = *(const float4*)(row + d0);
      zqT[(d0 + 0) * 33 + nl] = v.x;
      zqT[(d0 + 1) * 33 + nl] = v.y;
      zqT[(d0 + 2) * 33 + nl] = v.z;
      zqT[(d0 + 3) * 33 + nl] = v.w;
    }
    if (t < 32)
      idxf[nbase + t] = (float)(unsigned)(packed[nbase + t] & 0xFFFFFFFFull);
  }
  __syncthreads();

  const int w = t & 31, cg = t >> 5;
  const size_t base = (size_t)(blk >> 5) * 262144 + (size_t)(blk & 31) * 32 + w;
  float local = 0.f;
#pragma unroll
  for (int cc = 0; cc < 32; ++cc) {
    const int c = cg * 32 + cc;
    const float q  = zqT[c * 33 + w];
    const float zv = z[base + (size_t)c * 1024];
    out[base + (size_t)c * 1024] = q;
    const float dd = q - zv;
    local = fmaf(dd, dd, local);
  }
  float v = local;
#pragma unroll
  for (int m = 1; m < 64; m <<= 1) v += __shfl_xor(v, m, 64);
  if ((t & 63) == 0) part[t >> 6] = v;
  __syncthreads();
  if (t == 0) atomicAdd(ssum, part[0] + part[1] + part[2] + part[3]);
}

// ---- K4: finalize scalars ----
__global__ void k_final(const float* __restrict__ ssum, float* __restrict__ scal) {
  const float m = *ssum * INV_M;
  scal[0] = 1.25f * m;   // loss
  scal[1] = 0.25f * m;   // commitment_loss
  scal[2] = m;           // codebook_loss
}

extern "C" void kernel_launch(void* const* d_in, const int* in_sizes, int n_in,
                              void* d_out, int out_size, void* d_ws, size_t ws_size,
                              hipStream_t stream) {
  const float* z    = (const float*)d_in[0];
  const float* emb  = (const float*)d_in[1];
  const float* proj = (const float*)d_in[2];

  float* out  = (float*)d_out;
  float* scal = out + 4194304;
  float* idxf = out + 4194307;

  // ws (~28.9 MB): cb | norms | packed | znorm | zf | ef | rowminG | rowcnt | slots(u32) | ssum
  float* cb    = (float*)d_ws;                          // 8 MB
  float* norms = cb + 2097152;                          // 32 KB
  unsigned long long* packed =
      (unsigned long long*)(norms + 8192);              // 128 KB
  float* znorm = (float*)(packed + 16384);              // 64 KB
  u16* zf = (u16*)(znorm + 16384);                      // 8.4 MB (fragment-order)
  u16* ef = zf + 4194304;                               // 4.2 MB (fragment-order)
  u32* rowminG = (u32*)(ef + 2097152);                  // 64 KB
  u32* rowcnt = rowminG + 16384;                        // 64 KB
  u32* slots = rowcnt + 16384;                          // 8 MB (128 u32/row)
  float* ssum = (float*)(slots + (size_t)16384 * SLOTS);// 4 B

  hipMemsetAsync(rowminG, 0xFF, 16384 * sizeof(u32), stream);
  hipMemsetAsync(rowcnt, 0, 16384 * sizeof(u32), stream);
  hipMemsetAsync(packed, 0xFF, 16384 * sizeof(unsigned long long), stream);
  hipMemsetAsync(ssum, 0, sizeof(float), stream);

  k_codebook<<<dim3(128, 4), 256, 0, stream>>>(emb, proj, cb, ef);
  k_norms   <<<32, 256, 0, stream>>>(cb, norms);
  k_prep_z  <<<512, 256, 0, stream>>>(z, zf, znorm);
  k_scan    <<<2048, 256, 0, stream>>>(zf, ef, norms, znorm,
                                       rowminG, rowcnt, slots);
  k_rescore <<<512, 256, 0, stream>>>(z, cb, norms, znorm,
                                      rowminG, rowcnt, slots, packed);
  k_output  <<<512, 256, 0, stream>>>(z, cb, packed, out, idxf, ssum);
  k_final   <<<1, 1, 0, stream>>>(ssum, scal);

  (void)in_sizes; (void)n_in; (void)out_size; (void)ws_size;
}

// Round 14
// 350.329 us; speedup vs baseline: 1.3271x; 1.0330x over previous
//
#include <hip/hip_runtime.h>
#include <cfloat>

// VQ forward, MI355X. z[16,256,32,32] f32, emb[8192,256] f32, proj[256,256] f32.
// N = 16384 rows, K = 8192 codes, D = 256.
// d_out (floats): out[4194304] | loss | commitment | codebook_loss | idx_as_float[16384]
//
// R17 (393): single-pass scan, running-threshold emission, score-carrying slots
//  (quant19(sc-zn)<<13|k), final-threshold-filtered exact rescore.
// R18 (387): A-resident regs + k_codebook float4. R19 (REVERTED): async
//  exchange doubled emissions. R20 (374): distance-4 B pipeline, no barriers.
// R21 (362): A -> 32KB LDS tile (staged once), B dist-2, (256,4). Occupancy
//  21->41% won -12 us DESPITE the spill falsifier firing: 128-reg cap vs ~150
//  live -> WRITE 21->167 MB scratch, VGPR=64. Occupancy is the lever; the tax
//  is the spill.
// R22: ONE change — __launch_bounds__(256,3). The occupancy brackets (waves
//  halve at 64/128/256 regs) admit a midpoint: 3 waves/SIMD at cap 170.
//  Live set ~140-150 (acc32+Bb32+As16+zn8+ptrs/temps) fits with headroom ->
//  no spill + 3 blocks/CU (LDS 96KB <= 160). Falsifiers: WRITE must drop to
//  ~21 MB, FETCH to ~35 GB, VGPR ~150-170. Everything else identical to R21.

constexpr int Dd = 256;
constexpr float INV_M = 1.0f / 4194304.0f;
constexpr float DLT = 8e-4f;
constexpr int SLOTS = 128;

typedef unsigned short u16;
typedef unsigned int u32;
typedef __attribute__((ext_vector_type(8))) short short8;   // 8 bf16
typedef __attribute__((ext_vector_type(4))) float f32x4;

#define GLOBAL_AS __attribute__((address_space(1)))
#define LDS_AS    __attribute__((address_space(3)))

__device__ __forceinline__ unsigned monof(float f) {
  unsigned u = __float_as_uint(f);
  return (u & 0x80000000u) ? ~u : (u | 0x80000000u);
}
__device__ __forceinline__ float unmonof(unsigned p) {
  unsigned u = (p & 0x80000000u) ? (p & 0x7FFFFFFFu) : ~p;
  return __uint_as_float(u);
}
__device__ __forceinline__ u16 f2bf(float x) {   // RNE float->bf16 bits
  unsigned u = __float_as_uint(x);
  u += 0x7FFFu + ((u >> 16) & 1u);
  return (u16)(u >> 16);
}

// ---- K1: codebook = emb @ proj^T -> cb[k][d] fp32 + ef bf16 fragment-order ----
__global__ __launch_bounds__(256)
void k_codebook(const float* __restrict__ emb, const float* __restrict__ proj,
                float* __restrict__ cb, u16* __restrict__ ef) {
  __shared__ __align__(16) float et[64 * 68];
  __shared__ __align__(16) float pt[64 * 68];
  __shared__ __align__(16) u16 tileT[64 * 72];
  const int t = threadIdx.x;
  const int tx = t & 15, ty = t >> 4;
  const int kb = blockIdx.x * 64;
  const int db = blockIdx.y * 64;
  float acc[4][4];
#pragma unroll
  for (int u = 0; u < 4; ++u)
#pragma unroll
    for (int v = 0; v < 4; ++v) acc[u][v] = 0.f;

  const int jm = t & 15;
  const int q  = t >> 4;

  for (int jc = 0; jc < Dd; jc += 64) {
    __syncthreads();
#pragma unroll
    for (int i = 0; i < 4; ++i) {
      const int row = q + i * 16;
      const float4 e4 = *(const float4*)(emb  + (size_t)(kb + row) * Dd + jc + jm * 4);
      const float4 p4 = *(const float4*)(proj + (size_t)(db + row) * Dd + jc + jm * 4);
      et[(jm*4 + 0) * 68 + row] = e4.x;
      et[(jm*4 + 1) * 68 + row] = e4.y;
      et[(jm*4 + 2) * 68 + row] = e4.z;
      et[(jm*4 + 3) * 68 + row] = e4.w;
      pt[(jm*4 + 0) * 68 + row] = p4.x;
      pt[(jm*4 + 1) * 68 + row] = p4.y;
      pt[(jm*4 + 2) * 68 + row] = p4.z;
      pt[(jm*4 + 3) * 68 + row] = p4.w;
    }
    __syncthreads();
#pragma unroll 16
    for (int j = 0; j < 64; ++j) {
      const float4 a4 = *(const float4*)(et + j * 68 + ty * 4);
      const float4 b4 = *(const float4*)(pt + j * 68 + tx * 4);
      const float a[4] = {a4.x, a4.y, a4.z, a4.w};
      const float b[4] = {b4.x, b4.y, b4.z, b4.w};
#pragma unroll
      for (int u = 0; u < 4; ++u)
#pragma unroll
        for (int v = 0; v < 4; ++v) acc[u][v] = fmaf(a[u], b[v], acc[u][v]);
    }
  }
  // fp32 cb (linear) + bf16 tile to LDS for fragment-order shuffle
#pragma unroll
  for (int u = 0; u < 4; ++u) {
    const int k = kb + ty*4 + u;
#pragma unroll
    for (int v = 0; v < 4; ++v) {
      const int d = db + tx*4 + v;
      const float val = acc[u][v];
      cb[(size_t)k * Dd + d] = val;
      tileT[(ty*4 + u) * 72 + tx*4 + v] = f2bf(val);
    }
  }
  __syncthreads();
  // emit 512 fragment granules (16 B each), coalesced
  uint4* ef16 = (uint4*)ef;
#pragma unroll
  for (int w2 = 0; w2 < 2; ++w2) {
    const int uu = w2 * 256 + t;
    const int k16g = uu >> 7;            // 0..3 (16-k group within tile)
    const int d32g = (uu >> 6) & 1;      // 0..1 (32-d group within tile)
    const int ln   = uu & 63;            // fragment lane
    const int klo  = k16g * 16 + (ln & 15);
    const int dlo  = d32g * 32 + (ln >> 4) * 8;
    ef16[((kb >> 4) + k16g) * 512 + ((db >> 5) + d32g) * 64 + ln] =
        *(const uint4*)&tileT[klo * 72 + dlo];
  }
}

// ---- K1b: per-code norms (ascending-d fmaf chain) ----
__global__ __launch_bounds__(256)
void k_norms(const float* __restrict__ cb, float* __restrict__ norms) {
  const int k = blockIdx.x * 256 + threadIdx.x;
  const float* row = cb + (size_t)k * Dd;
  float s = 0.f;
  for (int d = 0; d < Dd; d += 4) {
    const float4 v = *(const float4*)(row + d);
    s = fmaf(v.x, v.x, s);
    s = fmaf(v.y, v.y, s);
    s = fmaf(v.z, v.z, s);
    s = fmaf(v.w, v.w, s);
  }
  norms[k] = s;
}

// ---- K1c: transpose z -> zf bf16 fragment-order + znorm ----
__global__ __launch_bounds__(256)
void k_prep_z(const float* __restrict__ z, u16* __restrict__ zf,
              float* __restrict__ znorm) {
  __shared__ float tile[256 * 33];
  const int t = threadIdx.x;
  const int blk = blockIdx.x;            // b*32 + h
  const int w = t & 31, rg = t >> 5;
  const size_t zbase = (size_t)(blk >> 5) * 262144 + (size_t)(blk & 31) * 32 + w;
#pragma unroll 8
  for (int i = 0; i < 32; ++i) {
    const int d = rg * 32 + i;
    tile[d * 33 + w] = z[zbase + (size_t)d * 1024];
  }
  __syncthreads();
  if (t < 32) {
    float s = 0.f;
    for (int d = 0; d < Dd; ++d) {
      const float v = tile[d * 33 + t];
      s = fmaf(v, v, s);
    }
    znorm[blk * 32 + t] = s;
  }
  // fragment-order write: granule U = ((n>>4)*8 + d32)*64 + qd*16 + (n&15)
  const int ml16 = t & 15;
  const int seg  = (t >> 4) & 7;         // d32 group
  const int hi   = t >> 7;               // n16 group within block (0/1)
  const int nl   = hi * 16 + ml16;       // row 0..31 within block
  uint4* zf16 = (uint4*)zf;
  const int ubase = ((blk * 2 + hi) * 8 + seg) * 64 + ml16;
#pragma unroll
  for (int j = 0; j < 4; ++j) {          // qd octet
    u16 hb[8];
#pragma unroll
    for (int e = 0; e < 8; ++e)
      hb[e] = f2bf(tile[(seg * 32 + j * 8 + e) * 33 + nl]);
    zf16[ubase + j * 16] = *(const uint4*)hb;
  }
}

// ---- K2: single-pass MFMA scan; A in LDS (staged once), B dist-2 reg pipe ----
// Block 64 rows x 1024 cols; wave (rowhalf,colhalf) = 32 rows x 128 cols.
// 3 blocks/CU target: regs <= 170 (live ~150, headroom), LDS 96 KB.
__global__ __launch_bounds__(256, 3)
void k_scan(const u16* __restrict__ zf, const u16* __restrict__ ef,
            const float* __restrict__ norms, const float* __restrict__ znorm,
            u32* __restrict__ rowminG, u32* __restrict__ rowcnt,
            u32* __restrict__ slots) {
  __shared__ __align__(16) u16 zsh[64 * 256];   // 32 KB A tile (fragment order)
  const int t    = threadIdx.x;
  const int lane = t & 63;
  const int ml   = lane & 15;
  const int qd   = lane >> 4;
  const int wvu  = __builtin_amdgcn_readfirstlane(t >> 6);
  const int rowhalf = wvu & 1;           // 0/1 -> 32 rows
  const int colhalf = wvu >> 1;          // 0/1 -> 128 cols (of kt's 256)
  const int bid  = blockIdx.x;
  const int kb   = (bid & 7) * 1024;     // colgroup -> XCD-local ef reuse
  const int nb   = (bid >> 3) * 64;

  const uint4* zf16 = (const uint4*)zf;
  const uint4* ef16 = (const uint4*)ef;

  // ---- stage A once: block rows are contiguous granules in fragment order ----
  {
    const uint4* zsrc = zf16 + (size_t)(nb >> 4) * 512;
#pragma unroll
    for (int i = 0; i < 8; ++i) {
      const int g = wvu * 512 + i * 64;    // wave's 8 x 1KB chunks
      __builtin_amdgcn_global_load_lds((const GLOBAL_AS void*)(zsrc + g + lane),
                                       (LDS_AS void*)(zsh + (size_t)g * 8), 16, 0, 0);
    }
  }
  __syncthreads();   // the ONLY barrier: A tile ready; LDS read-only hereafter

  // A granule (rt, d): u16 offset ((rowhalf*2+rt)*8 + d)*512 + lane*8 (stride-1)
  const u16* ab0 = zsh + (size_t)((rowhalf * 2 + 0) * 8) * 512 + lane * 8;
  const u16* ab1 = zsh + (size_t)((rowhalf * 2 + 1) * 8) * 512 + lane * 8;

  // B granule (kt,cq,ct,d32): eb + ((kt*16)+(cq*4)+ct)*512 + d32*64
  const uint4* eb = ef16 + (size_t)((kb >> 4) + colhalf * 8) * 512 + lane;

  // per-thread rows: n = nb + rowhalf*32 + rt*16 + qd*4 + r
  float zn[2][4];
#pragma unroll
  for (int rt = 0; rt < 2; ++rt) {
    const int nr = nb + rowhalf * 32 + rt * 16 + qd * 4;
    const f32x4 z4 = *(const f32x4*)(znorm + nr);
#pragma unroll
    for (int r = 0; r < 4; ++r) zn[rt][r] = z4[r];
  }

  // ---- A double buffer (1-step lookahead) + B distance-2 pipeline ----
  short8 As0[2], As1[2], Bb0[4], Bb1[4];
  As0[0] = *(const short8*)(ab0);            // d32 = 0
  As0[1] = *(const short8*)(ab1);
#pragma unroll
  for (int ct = 0; ct < 4; ++ct) {           // steps 0,1 (kt=0,cq=0)
    Bb0[ct] = *(const short8*)(eb + ct * 512);
    Bb1[ct] = *(const short8*)(eb + ct * 512 + 64);
  }

#pragma unroll 1
  for (int kt = 0; kt < 4; ++kt) {
    const size_t ekt = (size_t)kt * 16 * 512;
#pragma unroll
    for (int cq = 0; cq < 2; ++cq) {
      const uint4* ecq = eb + ekt + (size_t)(cq * 4) * 512;

      f32x4 acc[2][4];
#pragma unroll
      for (int rt = 0; rt < 2; ++rt)
#pragma unroll
        for (int ct = 0; ct < 4; ++ct) acc[rt][ct] = (f32x4)0.f;

#pragma unroll
      for (int d32 = 0; d32 < 8; ++d32) {
        // A prefetch: next step's granule into the OTHER parity buffer.
        // A depends only on d32 -> (d32+1)&7 is correct across quad bounds.
        const int dn = (d32 + 1) & 7;
        if (d32 & 1) {
          As0[0] = *(const short8*)(ab0 + dn * 512);
          As0[1] = *(const short8*)(ab1 + dn * 512);
        } else {
          As1[0] = *(const short8*)(ab0 + dn * 512);
          As1[1] = *(const short8*)(ab1 + dn * 512);
        }
        // consume parity d32&1
        if (d32 & 1) {
#pragma unroll
          for (int ct = 0; ct < 4; ++ct)
#pragma unroll
            for (int rt = 0; rt < 2; ++rt)
              acc[rt][ct] = __builtin_amdgcn_mfma_f32_16x16x32_bf16(
                  As1[rt], Bb1[ct], acc[rt][ct], 0, 0, 0);
        } else {
#pragma unroll
          for (int ct = 0; ct < 4; ++ct)
#pragma unroll
            for (int rt = 0; rt < 2; ++rt)
              acc[rt][ct] = __builtin_amdgcn_mfma_f32_16x16x32_bf16(
                  As0[rt], Bb0[ct], acc[rt][ct], 0, 0, 0);
        }
        // B refill: step s+2 into the SAME parity buffer (after consumption)
        const bool lastB = (kt == 3) && (cq == 1) && (d32 >= 6);
        if (!lastB) {
          const uint4* pn;
          if (d32 < 6) {
            pn = ecq + (d32 + 2) * 64;                          // same quad
          } else if (cq == 0) {
            pn = eb + ekt + (size_t)4 * 512 + (d32 - 6) * 64;   // quad cq=1
          } else {
            pn = eb + ekt + (size_t)16 * 512 + (d32 - 6) * 64;  // next kt, cq=0
          }
          if (d32 & 1) {
#pragma unroll
            for (int ct = 0; ct < 4; ++ct)
              Bb1[ct] = *(const short8*)(pn + ct * 512);
          } else {
#pragma unroll
            for (int ct = 0; ct < 4; ++ct)
              Bb0[ct] = *(const short8*)(pn + ct * 512);
          }
        }
      }

      // ---- scores in place: acc = (zn + nk) - 2*acc  (quantized fold) ----
#pragma unroll
      for (int ct = 0; ct < 4; ++ct) {
        const int k0 = kb + kt * 256 + colhalf * 128 + cq * 64 + ct * 16 + ml;
        const float nkv = norms[k0];
#pragma unroll
        for (int rt = 0; rt < 2; ++rt)
#pragma unroll
          for (int r = 0; r < 4; ++r)
            acc[rt][ct][r] = (zn[rt][r] + nkv) - 2.0f * acc[rt][ct][r];
      }

      // ---- per-row quad min (over ct, then over 16 ml lanes) ----
      float m2[2][4];
#pragma unroll
      for (int rt = 0; rt < 2; ++rt)
#pragma unroll
        for (int r = 0; r < 4; ++r) {
          float m = fminf(fminf(acc[rt][0][r], acc[rt][1][r]),
                          fminf(acc[rt][2][r], acc[rt][3][r]));
#pragma unroll
          for (int s = 1; s < 16; s <<= 1) m = fminf(m, __shfl_xor(m, s, 64));
          m2[rt][r] = m;
        }

      // ---- sync atomicMin exchange (freshest threshold; R19 lesson) ----
      unsigned myg = 0xFFFFFFFFu;
      if (ml < 8) {
        const int rt_ = ml >> 2, r_ = ml & 3;
        const int n = nb + rowhalf * 32 + rt_ * 16 + qd * 4 + r_;
        const unsigned pk = monof(m2[rt_][r_]);
        const unsigned old = atomicMin(&rowminG[n], pk);
        myg = min(old, pk);
      }
      float thrv[2][4];
#pragma unroll
      for (int rt = 0; rt < 2; ++rt)
#pragma unroll
        for (int r = 0; r < 4; ++r) {
          const unsigned gg = __shfl(myg, (lane & 48) + rt * 4 + r, 64);
          thrv[rt][r] = unmonof(gg) + DLT;
        }

      // ---- emit candidates: sc <= freshest-global-min + DLT ----
      // slot payload: quant19(sc - zn) << 13 | k  (Sterbenz-exact sc-zn, 2^-21 res)
#pragma unroll
      for (int ct = 0; ct < 4; ++ct) {
        const int k = kb + kt * 256 + colhalf * 128 + cq * 64 + ct * 16 + ml;
#pragma unroll
        for (int rt = 0; rt < 2; ++rt)
#pragma unroll
          for (int r = 0; r < 4; ++r) {
            if (acc[rt][ct][r] <= thrv[rt][r]) {
              const int n = nb + rowhalf * 32 + rt * 16 + qd * 4 + r;
              const u32 pos = atomicAdd(&rowcnt[n], 1u);
              if (pos < (u32)SLOTS) {
                const float e = acc[rt][ct][r] - zn[rt][r];
                int q = __float2int_rn(e * 2097152.0f) + 262144;
                q = q < 0 ? 0 : (q > 524287 ? 524287 : q);
                slots[n * SLOTS + pos] = ((u32)q << 13) | (u32)k;
              }
            }
          }
      }
    }
    // no __syncthreads: LDS is read-only after staging; pipelines span quads.
  }
}

// ---- K2c: filtered exact rescore (full-scan fallback on overflow) ----
// Block per (b,h): 32 rows; LDS z-tile [32][261] fp32; wave per 8 rows.
__global__ __launch_bounds__(256)
void k_rescore(const float* __restrict__ z, const float* __restrict__ cb,
               const float* __restrict__ norms, const float* __restrict__ znorm,
               const u32* __restrict__ rowminG, const u32* __restrict__ rowcnt,
               const u32* __restrict__ slots,
               unsigned long long* __restrict__ packed) {
  __shared__ float ztl[32 * 261];
  const int t = threadIdx.x;
  const int blk = blockIdx.x;          // b*32 + h
  const int w = t & 31, dg = t >> 5;
  const size_t zbase = (size_t)(blk >> 5) * 262144 + (size_t)(blk & 31) * 32;
#pragma unroll 8
  for (int i = 0; i < 32; ++i) {
    const int d = dg * 32 + i;
    ztl[w * 261 + d] = z[zbase + (size_t)d * 1024 + w];
  }
  __syncthreads();

  const int lane = t & 63;
  const int wv = t >> 6;               // 4 waves
  // 4 waves x 8 rows each
#pragma unroll 1
  for (int i = 0; i < 8; ++i) {
    const int rl = wv * 8 + i;
    const int n = blk * 32 + rl;
    const u32 cnt = rowcnt[n];
    const float znr = znorm[n];
    const float* zp = ztl + rl * 261 + lane * 4;
    // final-threshold filter in encoded domain (+68 LSB covers all rounding)
    const float g = unmonof(rowminG[n]);
    const int qThr = __float2int_rn((g + DLT - znr) * 2097152.0f) + 262144 + 68;
    unsigned long long best = 0xFFFFFFFFFFFFFFFFull;
    if (cnt <= (u32)SLOTS) {
      for (u32 c = 0; c < cnt; ++c) {
        const u32 v = slots[n * SLOTS + c];      // wave-uniform addr -> broadcast
        if ((int)(v >> 13) > qThr) continue;     // uniform branch
        const int k = (int)(v & 8191u);
        const float4 c4 = *(const float4*)(cb + (size_t)k * Dd + lane * 4);
        float p = 0.f;
        p = fmaf(zp[0], c4.x, p);
        p = fmaf(zp[1], c4.y, p);
        p = fmaf(zp[2], c4.z, p);
        p = fmaf(zp[3], c4.w, p);
#pragma unroll
        for (int s = 1; s < 64; s <<= 1) p += __shfl_xor(p, s, 64);
        const float sc = (znr + norms[k]) - 2.0f * p;   // quantized fold
        const unsigned long long pk =
            ((unsigned long long)monof(sc) << 32) | (unsigned)k;
        if (pk < best) best = pk;                        // ties -> min k
      }
    } else {
      // overflow fallback (never expected): exact scan of all 8192 codes
      for (int k = 0; k < 8192; ++k) {
        const float4 c4 = *(const float4*)(cb + (size_t)k * Dd + lane * 4);
        float p = 0.f;
        p = fmaf(zp[0], c4.x, p);
        p = fmaf(zp[1], c4.y, p);
        p = fmaf(zp[2], c4.z, p);
        p = fmaf(zp[3], c4.w, p);
#pragma unroll
        for (int s = 1; s < 64; s <<= 1) p += __shfl_xor(p, s, 64);
        const float sc = (znr + norms[k]) - 2.0f * p;
        const unsigned long long pk =
            ((unsigned long long)monof(sc) << 32) | (unsigned)k;
        if (pk < best) best = pk;
      }
    }
    if (lane == 0 && cnt > 0) packed[n] = best;
  }
}

// ---- K3: gather codes, write out (NCHW), idx floats, reduce SSE ----
__global__ __launch_bounds__(256)
void k_output(const float* __restrict__ z, const float* __restrict__ cb,
              const unsigned long long* __restrict__ packed,
              float* __restrict__ out, float* __restrict__ idxf,
              float* __restrict__ ssum) {
  __shared__ float zqT[256 * 33];
  __shared__ float part[4];
  const int t = threadIdx.x;
  const int blk = blockIdx.x;       // = b*32 + h
  const int nbase = blk * 32;

  {
    const int nl = t >> 3, m = t & 7;
    // guard the GATHER address only (&8191): if upstream ever leaves the
    // sentinel, we return wrong values (checker catches) instead of faulting.
    const int idx = (int)(packed[nbase + nl] & 0xFFFFFFFFull) & 8191;
    const float* row = cb + (size_t)idx * Dd;
#pragma unroll
    for (int i = 0; i < 8; ++i) {
      const int d0 = m * 4 + i * 32;
      const float4 v = *(const float4*)(row + d0);
      zqT[(d0 + 0) * 33 + nl] = v.x;
      zqT[(d0 + 1) * 33 + nl] = v.y;
      zqT[(d0 + 2) * 33 + nl] = v.z;
      zqT[(d0 + 3) * 33 + nl] = v.w;
    }
    if (t < 32)
      idxf[nbase + t] = (float)(unsigned)(packed[nbase + t] & 0xFFFFFFFFull);
  }
  __syncthreads();

  const int w = t & 31, cg = t >> 5;
  const size_t base = (size_t)(blk >> 5) * 262144 + (size_t)(blk & 31) * 32 + w;
  float local = 0.f;
#pragma unroll
  for (int cc = 0; cc < 32; ++cc) {
    const int c = cg * 32 + cc;
    const float q  = zqT[c * 33 + w];
    const float zv = z[base + (size_t)c * 1024];
    out[base + (size_t)c * 1024] = q;
    const float dd = q - zv;
    local = fmaf(dd, dd, local);
  }
  float v = local;
#pragma unroll
  for (int m = 1; m < 64; m <<= 1) v += __shfl_xor(v, m, 64);
  if ((t & 63) == 0) part[t >> 6] = v;
  __syncthreads();
  if (t == 0) atomicAdd(ssum, part[0] + part[1] + part[2] + part[3]);
}

// ---- K4: finalize scalars ----
__global__ void k_final(const float* __restrict__ ssum, float* __restrict__ scal) {
  const float m = *ssum * INV_M;
  scal[0] = 1.25f * m;   // loss
  scal[1] = 0.25f * m;   // commitment_loss
  scal[2] = m;           // codebook_loss
}

extern "C" void kernel_launch(void* const* d_in, const int* in_sizes, int n_in,
                              void* d_out, int out_size, void* d_ws, size_t ws_size,
                              hipStream_t stream) {
  const float* z    = (const float*)d_in[0];
  const float* emb  = (const float*)d_in[1];
  const float* proj = (const float*)d_in[2];

  float* out  = (float*)d_out;
  float* scal = out + 4194304;
  float* idxf = out + 4194307;

  // ws (~28.9 MB): cb | norms | packed | znorm | zf | ef | rowminG | rowcnt | slots(u32) | ssum
  float* cb    = (float*)d_ws;                          // 8 MB
  float* norms = cb + 2097152;                          // 32 KB
  unsigned long long* packed =
      (unsigned long long*)(norms + 8192);              // 128 KB
  float* znorm = (float*)(packed + 16384);              // 64 KB
  u16* zf = (u16*)(znorm + 16384);                      // 8.4 MB (fragment-order)
  u16* ef = zf + 4194304;                               // 4.2 MB (fragment-order)
  u32* rowminG = (u32*)(ef + 2097152);                  // 64 KB
  u32* rowcnt = rowminG + 16384;                        // 64 KB
  u32* slots = rowcnt + 16384;                          // 8 MB (128 u32/row)
  float* ssum = (float*)(slots + (size_t)16384 * SLOTS);// 4 B

  hipMemsetAsync(rowminG, 0xFF, 16384 * sizeof(u32), stream);
  hipMemsetAsync(rowcnt, 0, 16384 * sizeof(u32), stream);
  hipMemsetAsync(packed, 0xFF, 16384 * sizeof(unsigned long long), stream);
  hipMemsetAsync(ssum, 0, sizeof(float), stream);

  k_codebook<<<dim3(128, 4), 256, 0, stream>>>(emb, proj, cb, ef);
  k_norms   <<<32, 256, 0, stream>>>(cb, norms);
  k_prep_z  <<<512, 256, 0, stream>>>(z, zf, znorm);
  k_scan    <<<2048, 256, 0, stream>>>(zf, ef, norms, znorm,
                                       rowminG, rowcnt, slots);
  k_rescore <<<512, 256, 0, stream>>>(z, cb, norms, znorm,
                                      rowminG, rowcnt, slots, packed);
  k_output  <<<512, 256, 0, stream>>>(z, cb, packed, out, idxf, ssum);
  k_final   <<<1, 1, 0, stream>>>(ssum, scal);

  (void)in_sizes; (void)n_in; (void)out_size; (void)ws_size;
}

// Round 15
// 335.656 us; speedup vs baseline: 1.3851x; 1.0437x over previous
//
#include <hip/hip_runtime.h>
#include <cfloat>

// VQ forward, MI355X. z[16,256,32,32] f32, emb[8192,256] f32, proj[256,256] f32.
// N = 16384 rows, K = 8192 codes, D = 256.
// d_out (floats): out[4194304] | loss | commitment | codebook_loss | idx_as_float[16384]
//
// R17 (393): single-pass scan, running-threshold emission, score-carrying slots
//  (quant19(sc-zn)<<13|k), final-threshold-filtered exact rescore.
// R18 (387): fragment-order operands everywhere. R19 (REVERTED): async exchange
//  doubled emissions. R20 (374): dist-4 B pipe. R21 (362): A->LDS tile, (256,4)
//  spilled hard (VGPR 64, WRITE 167 MB) but occupancy still won. R22 (350):
//  (256,3) -> VGPR 116 unified, scan 170; WRITE 41 MB = ~10 regs transient spill.
// R23: shave the transient peak, then request 4 waves/SIMD.
//  (1) A register double-buffer DROPPED (-16 regs, kills the cross-step lifetime
//      overlap that spilled): per d32 step, 2 direct ds_read_b128 (base + 16-bit
//      immediate; 120cyc latency covered by 4-wave TLP — the reason this change
//      pairs with the bounds change).
//  (2) __launch_bounds__(256,4): steady live ~100-110 <= 128 bracket. Differs
//      from R21's failed (256,4): ~20 fewer live regs, no A prefetch lifetimes.
//  Falsifiers: VGPR=64 / WRITE>100MB -> R21 pathology again -> revert to (256,3);
//  spill-free but scan >=165 -> occupancy saturated -> pivot to non-scan fusion.
//  Sync atomicMin exchange retained (R19: staleness doubles emissions).

constexpr int Dd = 256;
constexpr float INV_M = 1.0f / 4194304.0f;
constexpr float DLT = 8e-4f;
constexpr int SLOTS = 128;

typedef unsigned short u16;
typedef unsigned int u32;
typedef __attribute__((ext_vector_type(8))) short short8;   // 8 bf16
typedef __attribute__((ext_vector_type(4))) float f32x4;

#define GLOBAL_AS __attribute__((address_space(1)))
#define LDS_AS    __attribute__((address_space(3)))

__device__ __forceinline__ unsigned monof(float f) {
  unsigned u = __float_as_uint(f);
  return (u & 0x80000000u) ? ~u : (u | 0x80000000u);
}
__device__ __forceinline__ float unmonof(unsigned p) {
  unsigned u = (p & 0x80000000u) ? (p & 0x7FFFFFFFu) : ~p;
  return __uint_as_float(u);
}
__device__ __forceinline__ u16 f2bf(float x) {   // RNE float->bf16 bits
  unsigned u = __float_as_uint(x);
  u += 0x7FFFu + ((u >> 16) & 1u);
  return (u16)(u >> 16);
}

// ---- K1: codebook = emb @ proj^T -> cb[k][d] fp32 + ef bf16 fragment-order ----
__global__ __launch_bounds__(256)
void k_codebook(const float* __restrict__ emb, const float* __restrict__ proj,
                float* __restrict__ cb, u16* __restrict__ ef) {
  __shared__ __align__(16) float et[64 * 68];
  __shared__ __align__(16) float pt[64 * 68];
  __shared__ __align__(16) u16 tileT[64 * 72];
  const int t = threadIdx.x;
  const int tx = t & 15, ty = t >> 4;
  const int kb = blockIdx.x * 64;
  const int db = blockIdx.y * 64;
  float acc[4][4];
#pragma unroll
  for (int u = 0; u < 4; ++u)
#pragma unroll
    for (int v = 0; v < 4; ++v) acc[u][v] = 0.f;

  const int jm = t & 15;
  const int q  = t >> 4;

  for (int jc = 0; jc < Dd; jc += 64) {
    __syncthreads();
#pragma unroll
    for (int i = 0; i < 4; ++i) {
      const int row = q + i * 16;
      const float4 e4 = *(const float4*)(emb  + (size_t)(kb + row) * Dd + jc + jm * 4);
      const float4 p4 = *(const float4*)(proj + (size_t)(db + row) * Dd + jc + jm * 4);
      et[(jm*4 + 0) * 68 + row] = e4.x;
      et[(jm*4 + 1) * 68 + row] = e4.y;
      et[(jm*4 + 2) * 68 + row] = e4.z;
      et[(jm*4 + 3) * 68 + row] = e4.w;
      pt[(jm*4 + 0) * 68 + row] = p4.x;
      pt[(jm*4 + 1) * 68 + row] = p4.y;
      pt[(jm*4 + 2) * 68 + row] = p4.z;
      pt[(jm*4 + 3) * 68 + row] = p4.w;
    }
    __syncthreads();
#pragma unroll 16
    for (int j = 0; j < 64; ++j) {
      const float4 a4 = *(const float4*)(et + j * 68 + ty * 4);
      const float4 b4 = *(const float4*)(pt + j * 68 + tx * 4);
      const float a[4] = {a4.x, a4.y, a4.z, a4.w};
      const float b[4] = {b4.x, b4.y, b4.z, b4.w};
#pragma unroll
      for (int u = 0; u < 4; ++u)
#pragma unroll
        for (int v = 0; v < 4; ++v) acc[u][v] = fmaf(a[u], b[v], acc[u][v]);
    }
  }
  // fp32 cb (linear) + bf16 tile to LDS for fragment-order shuffle
#pragma unroll
  for (int u = 0; u < 4; ++u) {
    const int k = kb + ty*4 + u;
#pragma unroll
    for (int v = 0; v < 4; ++v) {
      const int d = db + tx*4 + v;
      const float val = acc[u][v];
      cb[(size_t)k * Dd + d] = val;
      tileT[(ty*4 + u) * 72 + tx*4 + v] = f2bf(val);
    }
  }
  __syncthreads();
  // emit 512 fragment granules (16 B each), coalesced
  uint4* ef16 = (uint4*)ef;
#pragma unroll
  for (int w2 = 0; w2 < 2; ++w2) {
    const int uu = w2 * 256 + t;
    const int k16g = uu >> 7;            // 0..3 (16-k group within tile)
    const int d32g = (uu >> 6) & 1;      // 0..1 (32-d group within tile)
    const int ln   = uu & 63;            // fragment lane
    const int klo  = k16g * 16 + (ln & 15);
    const int dlo  = d32g * 32 + (ln >> 4) * 8;
    ef16[((kb >> 4) + k16g) * 512 + ((db >> 5) + d32g) * 64 + ln] =
        *(const uint4*)&tileT[klo * 72 + dlo];
  }
}

// ---- K1b: per-code norms (ascending-d fmaf chain) ----
__global__ __launch_bounds__(256)
void k_norms(const float* __restrict__ cb, float* __restrict__ norms) {
  const int k = blockIdx.x * 256 + threadIdx.x;
  const float* row = cb + (size_t)k * Dd;
  float s = 0.f;
  for (int d = 0; d < Dd; d += 4) {
    const float4 v = *(const float4*)(row + d);
    s = fmaf(v.x, v.x, s);
    s = fmaf(v.y, v.y, s);
    s = fmaf(v.z, v.z, s);
    s = fmaf(v.w, v.w, s);
  }
  norms[k] = s;
}

// ---- K1c: transpose z -> zf bf16 fragment-order + znorm ----
__global__ __launch_bounds__(256)
void k_prep_z(const float* __restrict__ z, u16* __restrict__ zf,
              float* __restrict__ znorm) {
  __shared__ float tile[256 * 33];
  const int t = threadIdx.x;
  const int blk = blockIdx.x;            // b*32 + h
  const int w = t & 31, rg = t >> 5;
  const size_t zbase = (size_t)(blk >> 5) * 262144 + (size_t)(blk & 31) * 32 + w;
#pragma unroll 8
  for (int i = 0; i < 32; ++i) {
    const int d = rg * 32 + i;
    tile[d * 33 + w] = z[zbase + (size_t)d * 1024];
  }
  __syncthreads();
  if (t < 32) {
    float s = 0.f;
    for (int d = 0; d < Dd; ++d) {
      const float v = tile[d * 33 + t];
      s = fmaf(v, v, s);
    }
    znorm[blk * 32 + t] = s;
  }
  // fragment-order write: granule U = ((n>>4)*8 + d32)*64 + qd*16 + (n&15)
  const int ml16 = t & 15;
  const int seg  = (t >> 4) & 7;         // d32 group
  const int hi   = t >> 7;               // n16 group within block (0/1)
  const int nl   = hi * 16 + ml16;       // row 0..31 within block
  uint4* zf16 = (uint4*)zf;
  const int ubase = ((blk * 2 + hi) * 8 + seg) * 64 + ml16;
#pragma unroll
  for (int j = 0; j < 4; ++j) {          // qd octet
    u16 hb[8];
#pragma unroll
    for (int e = 0; e < 8; ++e)
      hb[e] = f2bf(tile[(seg * 32 + j * 8 + e) * 33 + nl]);
    zf16[ubase + j * 16] = *(const uint4*)hb;
  }
}

// ---- K2: single-pass MFMA scan; A in LDS (direct reads), B dist-2 reg pipe ----
// Block 64 rows x 1024 cols; wave (rowhalf,colhalf) = 32 rows x 128 cols.
// 4 blocks/CU target: steady live ~100-110 regs <= 128 bracket; LDS 32 KB.
__global__ __launch_bounds__(256, 4)
void k_scan(const u16* __restrict__ zf, const u16* __restrict__ ef,
            const float* __restrict__ norms, const float* __restrict__ znorm,
            u32* __restrict__ rowminG, u32* __restrict__ rowcnt,
            u32* __restrict__ slots) {
  __shared__ __align__(16) u16 zsh[64 * 256];   // 32 KB A tile (fragment order)
  const int t    = threadIdx.x;
  const int lane = t & 63;
  const int ml   = lane & 15;
  const int qd   = lane >> 4;
  const int wvu  = __builtin_amdgcn_readfirstlane(t >> 6);
  const int rowhalf = wvu & 1;           // 0/1 -> 32 rows
  const int colhalf = wvu >> 1;          // 0/1 -> 128 cols (of kt's 256)
  const int bid  = blockIdx.x;
  const int kb   = (bid & 7) * 1024;     // colgroup -> XCD-local ef reuse
  const int nb   = (bid >> 3) * 64;

  const uint4* zf16 = (const uint4*)zf;
  const uint4* ef16 = (const uint4*)ef;

  // ---- stage A once: block rows are contiguous granules in fragment order ----
  {
    const uint4* zsrc = zf16 + (size_t)(nb >> 4) * 512;
#pragma unroll
    for (int i = 0; i < 8; ++i) {
      const int g = wvu * 512 + i * 64;    // wave's 8 x 1KB chunks
      __builtin_amdgcn_global_load_lds((const GLOBAL_AS void*)(zsrc + g + lane),
                                       (LDS_AS void*)(zsh + (size_t)g * 8), 16, 0, 0);
    }
  }
  __syncthreads();   // the ONLY barrier: A tile ready; LDS read-only hereafter

  // A granule (rt, d): single base; offsets rt*8192 + d*1024 bytes fold into
  // the ds_read 16-bit immediate (max 15.3 KB).
  const u16* ab = zsh + (size_t)(rowhalf * 2 * 8) * 512 + lane * 8;

  // B granule (kt,cq,ct,d32): eb + ((kt*16)+(cq*4)+ct)*512 + d32*64
  const uint4* eb = ef16 + (size_t)((kb >> 4) + colhalf * 8) * 512 + lane;

  // per-thread rows: n = nb + rowhalf*32 + rt*16 + qd*4 + r
  float zn[2][4];
#pragma unroll
  for (int rt = 0; rt < 2; ++rt) {
    const int nr = nb + rowhalf * 32 + rt * 16 + qd * 4;
    const f32x4 z4 = *(const f32x4*)(znorm + nr);
#pragma unroll
    for (int r = 0; r < 4; ++r) zn[rt][r] = z4[r];
  }

  // ---- B distance-2 register pipeline (parity d32&1) ----
  short8 Bb0[4], Bb1[4];
#pragma unroll
  for (int ct = 0; ct < 4; ++ct) {           // steps 0,1 (kt=0,cq=0)
    Bb0[ct] = *(const short8*)(eb + ct * 512);
    Bb1[ct] = *(const short8*)(eb + ct * 512 + 64);
  }

#pragma unroll 1
  for (int kt = 0; kt < 4; ++kt) {
    const size_t ekt = (size_t)kt * 16 * 512;
#pragma unroll
    for (int cq = 0; cq < 2; ++cq) {
      const uint4* ecq = eb + ekt + (size_t)(cq * 4) * 512;

      f32x4 acc[2][4];
#pragma unroll
      for (int rt = 0; rt < 2; ++rt)
#pragma unroll
        for (int ct = 0; ct < 4; ++ct) acc[rt][ct] = (f32x4)0.f;

#pragma unroll
      for (int d32 = 0; d32 < 8; ++d32) {
        // A: direct per-step LDS reads (no double-buffer; 4-wave TLP covers)
        short8 As[2];
        As[0] = *(const short8*)(ab + d32 * 512);
        As[1] = *(const short8*)(ab + 4096 + d32 * 512);
        // consume B parity d32&1
        if (d32 & 1) {
#pragma unroll
          for (int ct = 0; ct < 4; ++ct)
#pragma unroll
            for (int rt = 0; rt < 2; ++rt)
              acc[rt][ct] = __builtin_amdgcn_mfma_f32_16x16x32_bf16(
                  As[rt], Bb1[ct], acc[rt][ct], 0, 0, 0);
        } else {
#pragma unroll
          for (int ct = 0; ct < 4; ++ct)
#pragma unroll
            for (int rt = 0; rt < 2; ++rt)
              acc[rt][ct] = __builtin_amdgcn_mfma_f32_16x16x32_bf16(
                  As[rt], Bb0[ct], acc[rt][ct], 0, 0, 0);
        }
        // B refill: step s+2 into the SAME parity buffer (after consumption)
        const bool lastB = (kt == 3) && (cq == 1) && (d32 >= 6);
        if (!lastB) {
          const uint4* pn;
          if (d32 < 6) {
            pn = ecq + (d32 + 2) * 64;                          // same quad
          } else if (cq == 0) {
            pn = eb + ekt + (size_t)4 * 512 + (d32 - 6) * 64;   // quad cq=1
          } else {
            pn = eb + ekt + (size_t)16 * 512 + (d32 - 6) * 64;  // next kt, cq=0
          }
          if (d32 & 1) {
#pragma unroll
            for (int ct = 0; ct < 4; ++ct)
              Bb1[ct] = *(const short8*)(pn + ct * 512);
          } else {
#pragma unroll
            for (int ct = 0; ct < 4; ++ct)
              Bb0[ct] = *(const short8*)(pn + ct * 512);
          }
        }
      }

      // ---- scores in place: acc = (zn + nk) - 2*acc  (quantized fold) ----
#pragma unroll
      for (int ct = 0; ct < 4; ++ct) {
        const int k0 = kb + kt * 256 + colhalf * 128 + cq * 64 + ct * 16 + ml;
        const float nkv = norms[k0];
#pragma unroll
        for (int rt = 0; rt < 2; ++rt)
#pragma unroll
          for (int r = 0; r < 4; ++r)
            acc[rt][ct][r] = (zn[rt][r] + nkv) - 2.0f * acc[rt][ct][r];
      }

      // ---- per-row quad min (over ct, then over 16 ml lanes) ----
      float m2[2][4];
#pragma unroll
      for (int rt = 0; rt < 2; ++rt)
#pragma unroll
        for (int r = 0; r < 4; ++r) {
          float m = fminf(fminf(acc[rt][0][r], acc[rt][1][r]),
                          fminf(acc[rt][2][r], acc[rt][3][r]));
#pragma unroll
          for (int s = 1; s < 16; s <<= 1) m = fminf(m, __shfl_xor(m, s, 64));
          m2[rt][r] = m;
        }

      // ---- sync atomicMin exchange (freshest threshold; R19 lesson) ----
      unsigned myg = 0xFFFFFFFFu;
      if (ml < 8) {
        const int rt_ = ml >> 2, r_ = ml & 3;
        const int n = nb + rowhalf * 32 + rt_ * 16 + qd * 4 + r_;
        const unsigned pk = monof(m2[rt_][r_]);
        const unsigned old = atomicMin(&rowminG[n], pk);
        myg = min(old, pk);
      }
      float thrv[2][4];
#pragma unroll
      for (int rt = 0; rt < 2; ++rt)
#pragma unroll
        for (int r = 0; r < 4; ++r) {
          const unsigned gg = __shfl(myg, (lane & 48) + rt * 4 + r, 64);
          thrv[rt][r] = unmonof(gg) + DLT;
        }

      // ---- emit candidates: sc <= freshest-global-min + DLT ----
      // slot payload: quant19(sc - zn) << 13 | k  (Sterbenz-exact sc-zn, 2^-21 res)
#pragma unroll
      for (int ct = 0; ct < 4; ++ct) {
        const int k = kb + kt * 256 + colhalf * 128 + cq * 64 + ct * 16 + ml;
#pragma unroll
        for (int rt = 0; rt < 2; ++rt)
#pragma unroll
          for (int r = 0; r < 4; ++r) {
            if (acc[rt][ct][r] <= thrv[rt][r]) {
              const int n = nb + rowhalf * 32 + rt * 16 + qd * 4 + r;
              const u32 pos = atomicAdd(&rowcnt[n], 1u);
              if (pos < (u32)SLOTS) {
                const float e = acc[rt][ct][r] - zn[rt][r];
                int q = __float2int_rn(e * 2097152.0f) + 262144;
                q = q < 0 ? 0 : (q > 524287 ? 524287 : q);
                slots[n * SLOTS + pos] = ((u32)q << 13) | (u32)k;
              }
            }
          }
      }
    }
    // no __syncthreads: LDS is read-only after staging; pipelines span quads.
  }
}

// ---- K2c: filtered exact rescore (full-scan fallback on overflow) ----
// Block per (b,h): 32 rows; LDS z-tile [32][261] fp32; wave per 8 rows.
__global__ __launch_bounds__(256)
void k_rescore(const float* __restrict__ z, const float* __restrict__ cb,
               const float* __restrict__ norms, const float* __restrict__ znorm,
               const u32* __restrict__ rowminG, const u32* __restrict__ rowcnt,
               const u32* __restrict__ slots,
               unsigned long long* __restrict__ packed) {
  __shared__ float ztl[32 * 261];
  const int t = threadIdx.x;
  const int blk = blockIdx.x;          // b*32 + h
  const int w = t & 31, dg = t >> 5;
  const size_t zbase = (size_t)(blk >> 5) * 262144 + (size_t)(blk & 31) * 32;
#pragma unroll 8
  for (int i = 0; i < 32; ++i) {
    const int d = dg * 32 + i;
    ztl[w * 261 + d] = z[zbase + (size_t)d * 1024 + w];
  }
  __syncthreads();

  const int lane = t & 63;
  const int wv = t >> 6;               // 4 waves
  // 4 waves x 8 rows each
#pragma unroll 1
  for (int i = 0; i < 8; ++i) {
    const int rl = wv * 8 + i;
    const int n = blk * 32 + rl;
    const u32 cnt = rowcnt[n];
    const float znr = znorm[n];
    const float* zp = ztl + rl * 261 + lane * 4;
    // final-threshold filter in encoded domain (+68 LSB covers all rounding)
    const float g = unmonof(rowminG[n]);
    const int qThr = __float2int_rn((g + DLT - znr) * 2097152.0f) + 262144 + 68;
    unsigned long long best = 0xFFFFFFFFFFFFFFFFull;
    if (cnt <= (u32)SLOTS) {
      for (u32 c = 0; c < cnt; ++c) {
        const u32 v = slots[n * SLOTS + c];      // wave-uniform addr -> broadcast
        if ((int)(v >> 13) > qThr) continue;     // uniform branch
        const int k = (int)(v & 8191u);
        const float4 c4 = *(const float4*)(cb + (size_t)k * Dd + lane * 4);
        float p = 0.f;
        p = fmaf(zp[0], c4.x, p);
        p = fmaf(zp[1], c4.y, p);
        p = fmaf(zp[2], c4.z, p);
        p = fmaf(zp[3], c4.w, p);
#pragma unroll
        for (int s = 1; s < 64; s <<= 1) p += __shfl_xor(p, s, 64);
        const float sc = (znr + norms[k]) - 2.0f * p;   // quantized fold
        const unsigned long long pk =
            ((unsigned long long)monof(sc) << 32) | (unsigned)k;
        if (pk < best) best = pk;                        // ties -> min k
      }
    } else {
      // overflow fallback (never expected): exact scan of all 8192 codes
      for (int k = 0; k < 8192; ++k) {
        const float4 c4 = *(const float4*)(cb + (size_t)k * Dd + lane * 4);
        float p = 0.f;
        p = fmaf(zp[0], c4.x, p);
        p = fmaf(zp[1], c4.y, p);
        p = fmaf(zp[2], c4.z, p);
        p = fmaf(zp[3], c4.w, p);
#pragma unroll
        for (int s = 1; s < 64; s <<= 1) p += __shfl_xor(p, s, 64);
        const float sc = (znr + norms[k]) - 2.0f * p;
        const unsigned long long pk =
            ((unsigned long long)monof(sc) << 32) | (unsigned)k;
        if (pk < best) best = pk;
      }
    }
    if (lane == 0 && cnt > 0) packed[n] = best;
  }
}

// ---- K3: gather codes, write out (NCHW), idx floats, reduce SSE ----
__global__ __launch_bounds__(256)
void k_output(const float* __restrict__ z, const float* __restrict__ cb,
              const unsigned long long* __restrict__ packed,
              float* __restrict__ out, float* __restrict__ idxf,
              float* __restrict__ ssum) {
  __shared__ float zqT[256 * 33];
  __shared__ float part[4];
  const int t = threadIdx.x;
  const int blk = blockIdx.x;       // = b*32 + h
  const int nbase = blk * 32;

  {
    const int nl = t >> 3, m = t & 7;
    // guard the GATHER address only (&8191): if upstream ever leaves the
    // sentinel, we return wrong values (checker catches) instead of faulting.
    const int idx = (int)(packed[nbase + nl] & 0xFFFFFFFFull) & 8191;
    const float* row = cb + (size_t)idx * Dd;
#pragma unroll
    for (int i = 0; i < 8; ++i) {
      const int d0 = m * 4 + i * 32;
      const float4 v = *(const float4*)(row + d0);
      zqT[(d0 + 0) * 33 + nl] = v.x;
      zqT[(d0 + 1) * 33 + nl] = v.y;
      zqT[(d0 + 2) * 33 + nl] = v.z;
      zqT[(d0 + 3) * 33 + nl] = v.w;
    }
    if (t < 32)
      idxf[nbase + t] = (float)(unsigned)(packed[nbase + t] & 0xFFFFFFFFull);
  }
  __syncthreads();

  const int w = t & 31, cg = t >> 5;
  const size_t base = (size_t)(blk >> 5) * 262144 + (size_t)(blk & 31) * 32 + w;
  float local = 0.f;
#pragma unroll
  for (int cc = 0; cc < 32; ++cc) {
    const int c = cg * 32 + cc;
    const float q  = zqT[c * 33 + w];
    const float zv = z[base + (size_t)c * 1024];
    out[base + (size_t)c * 1024] = q;
    const float dd = q - zv;
    local = fmaf(dd, dd, local);
  }
  float v = local;
#pragma unroll
  for (int m = 1; m < 64; m <<= 1) v += __shfl_xor(v, m, 64);
  if ((t & 63) == 0) part[t >> 6] = v;
  __syncthreads();
  if (t == 0) atomicAdd(ssum, part[0] + part[1] + part[2] + part[3]);
}

// ---- K4: finalize scalars ----
__global__ void k_final(const float* __restrict__ ssum, float* __restrict__ scal) {
  const float m = *ssum * INV_M;
  scal[0] = 1.25f * m;   // loss
  scal[1] = 0.25f * m;   // commitment_loss
  scal[2] = m;           // codebook_loss
}

extern "C" void kernel_launch(void* const* d_in, const int* in_sizes, int n_in,
                              void* d_out, int out_size, void* d_ws, size_t ws_size,
                              hipStream_t stream) {
  const float* z    = (const float*)d_in[0];
  const float* emb  = (const float*)d_in[1];
  const float* proj = (const float*)d_in[2];

  float* out  = (float*)d_out;
  float* scal = out + 4194304;
  float* idxf = out + 4194307;

  // ws (~28.9 MB): cb | norms | packed | znorm | zf | ef | rowminG | rowcnt | slots(u32) | ssum
  float* cb    = (float*)d_ws;                          // 8 MB
  float* norms = cb + 2097152;                          // 32 KB
  unsigned long long* packed =
      (unsigned long long*)(norms + 8192);              // 128 KB
  float* znorm = (float*)(packed + 16384);              // 64 KB
  u16* zf = (u16*)(znorm + 16384);                      // 8.4 MB (fragment-order)
  u16* ef = zf + 4194304;                               // 4.2 MB (fragment-order)
  u32* rowminG = (u32*)(ef + 2097152);                  // 64 KB
  u32* rowcnt = rowminG + 16384;                        // 64 KB
  u32* slots = rowcnt + 16384;                          // 8 MB (128 u32/row)
  float* ssum = (float*)(slots + (size_t)16384 * SLOTS);// 4 B

  hipMemsetAsync(rowminG, 0xFF, 16384 * sizeof(u32), stream);
  hipMemsetAsync(rowcnt, 0, 16384 * sizeof(u32), stream);
  hipMemsetAsync(packed, 0xFF, 16384 * sizeof(unsigned long long), stream);
  hipMemsetAsync(ssum, 0, sizeof(float), stream);

  k_codebook<<<dim3(128, 4), 256, 0, stream>>>(emb, proj, cb, ef);
  k_norms   <<<32, 256, 0, stream>>>(cb, norms);
  k_prep_z  <<<512, 256, 0, stream>>>(z, zf, znorm);
  k_scan    <<<2048, 256, 0, stream>>>(zf, ef, norms, znorm,
                                       rowminG, rowcnt, slots);
  k_rescore <<<512, 256, 0, stream>>>(z, cb, norms, znorm,
                                      rowminG, rowcnt, slots, packed);
  k_output  <<<512, 256, 0, stream>>>(z, cb, packed, out, idxf, ssum);
  k_final   <<<1, 1, 0, stream>>>(ssum, scal);

  (void)in_sizes; (void)n_in; (void)out_size; (void)ws_size;
}